// Round 9
// baseline (683.230 us; speedup 1.0000x reference)
//
#include <hip/hip_runtime.h>
#include <stdint.h>

// RelationalMSG decomposed, 4 dispatches:
//   D1 k_pre:   zero bucket counters + convert W1/W2 -> MFMA B-frag layout (bf16)
//   D2 k_fat1:  block-split: gemm1 (Ys = x@W1a, Yd = x@W1b + b1, x cvt in-reg)
//               || bucket edge-binning: b=dst>>6; p=bcnt[b]++ (PADDED counter, line-
//               resident at its L3 slice); bslot[b*1024+p] = (dst&63)<<16 | src.
//               782 hot counters instead of 400K cold lines; stores hit ADJACENT
//               slots (coalescing lines) instead of 600K scattered 2B writes.
//   D3 k_agg:   one block per bucket: Yd rows + fp32 accumulator in LDS (48KB,
//               3 blocks/CU); waves stream packed edges (coalesced + shfl bcast),
//               gather Ys[src] rows, relu, fire-and-forget ds_add_f32. Epilogue
//               writes contiguous agg rows. No per-dst lists, no scan, no sort.
//   D4 k_gemm2: out = x + relu([x;agg]@W2 + b2)  (x cvt in-reg; no xb buffer)
// N=50000 (16 | N), E=600000, D=128. Edges/bucket ~Poisson(768), sigma 28:
// BCAP=1024 is 9 sigma (P overflow ~1e-19; clamped so it cannot corrupt memory).
// Lessons: no grid.sync (~50us/barrier); device atomics execute at the memory-side
// coherence point -> XCD-sharding counters is near-null (r8); scattered dependent
// stores cost ~30MB writeback (r8 WRITE_SIZE); contended-but-HOT counter lines are
// cheap (serialize at one slice, slices parallel).

typedef __attribute__((ext_vector_type(8))) short short8;   // 8 bf16 (MFMA A/B frag)
typedef __attribute__((ext_vector_type(4))) float floatx4;  // MFMA C/D frag

#define D 128
#define BSH 6              // 64 nodes per bucket
#define BNODES 64
#define BCAP 1024

static __device__ __forceinline__ unsigned short f2bf(float f) {
    union { float f; unsigned int u; } v; v.f = f;
    unsigned int r = (v.u + 0x7fffu + ((v.u >> 16) & 1u)) >> 16; // RNE
    return (unsigned short)r;
}
static __device__ __forceinline__ float bflo(unsigned int u) {
    union { unsigned int u; float f; } v; v.u = u << 16; return v.f;
}
static __device__ __forceinline__ float bfhi(unsigned int u) {
    union { unsigned int u; float f; } v; v.u = u & 0xffff0000u; return v.f;
}

// B-fragment layouts (column-PERMUTED so each lane's frags hold ADJACENT output cols):
// w1f (gemm1, K=128, 256 out cols): frag[(kk*16+ct)*64+lane][j] =
//      B1[kk*32+(lane>>4)*8+j][ (ct>>2)*64 + 4*(lane&15) + (ct&3) ]
//   B1[k][c] = c<128 ? W1[k][c] : W1[128+k][c-128]   (W1 is [256][128])
// w2f (gemm2, K=256, 128 out cols): frag[(kk*8+ct)*64+lane][j] =
//      W2[kk*32+(lane>>4)*8+j][ (ct>>1)*32 + 2*(lane&15) + (ct&1) ]
// Also zeroes the padded bucket counters (NB*16 ints).
__global__ void k_pre(const float* __restrict__ W1, const float* __restrict__ W2,
                      unsigned short* __restrict__ w1f, unsigned short* __restrict__ w2f,
                      int* __restrict__ bcnt, int N) {
    int gid = blockIdx.x * blockDim.x + threadIdx.x; // 65536 threads
    int nb16 = (((N + BNODES - 1) >> BSH) << 4);
    if (gid < nb16) bcnt[gid] = 0;
    if (gid < 32768) {
        int tid = gid;
        int j = tid & 7, lane = (tid >> 3) & 63, ct = (tid >> 9) & 15, kk = tid >> 13;
        int k = kk * 32 + (lane >> 4) * 8 + j;
        int c = ((ct >> 2) << 6) + ((lane & 15) << 2) + (ct & 3);
        float v = (c < 128) ? W1[k * 128 + c] : W1[(128 + k) * 128 + (c - 128)];
        w1f[tid] = f2bf(v);
    } else if (gid < 65536) {
        int tid = gid - 32768;
        int j = tid & 7, lane = (tid >> 3) & 63, ct = (tid >> 9) & 7, kk = tid >> 12;
        int k = kk * 32 + (lane >> 4) * 8 + j;
        int c = ((ct >> 1) << 5) + ((lane & 15) << 1) + (ct & 1);
        w2f[tid] = f2bf(W2[k * 128 + c]);
    }
}

// D2: blocks [0,nb1) = gemm1 (M=N, K=128, Nout=256); blocks [nb1,grid) = bucket
// edge-binning. gemm1: block = 4 waves; wave w owns out-cols [w*64,w*64+64).
// Frag j of wave w holds actual col w*64 + 4*(lane&15) + j  ->  8B ushort4 stores.
__global__ __launch_bounds__(256, 4) void k_fat1(
    const float* __restrict__ x,
    const unsigned short* __restrict__ w1f,
    const float* __restrict__ b1,
    unsigned short* __restrict__ Ys,
    unsigned short* __restrict__ Yd,
    const int* __restrict__ esrc,
    const int* __restrict__ edst,
    int* __restrict__ bcnt,
    unsigned int* __restrict__ bslot,
    int N, int nTiles, int nb1, int E)
{
    const int tid = threadIdx.x;
    if ((int)blockIdx.x >= nb1) {
        // ---- bucket edge-binning (one int4 edge-group per thread) ----
        const int hthreads = (gridDim.x - nb1) * 256;
        const int hid = (blockIdx.x - nb1) * 256 + tid;
        const int E4 = E >> 2;
        for (int i = hid; i < E4; i += hthreads) {
            int4 s4 = ((const int4*)esrc)[i];
            int4 d4 = ((const int4*)edst)[i];
            int p;
            p = atomicAdd(&bcnt[(d4.x >> BSH) << 4], 1);
            if (p < BCAP) bslot[((long)(d4.x >> BSH) << 10) + p] =
                ((unsigned int)(d4.x & (BNODES - 1)) << 16) | (unsigned int)s4.x;
            p = atomicAdd(&bcnt[(d4.y >> BSH) << 4], 1);
            if (p < BCAP) bslot[((long)(d4.y >> BSH) << 10) + p] =
                ((unsigned int)(d4.y & (BNODES - 1)) << 16) | (unsigned int)s4.y;
            p = atomicAdd(&bcnt[(d4.z >> BSH) << 4], 1);
            if (p < BCAP) bslot[((long)(d4.z >> BSH) << 10) + p] =
                ((unsigned int)(d4.z & (BNODES - 1)) << 16) | (unsigned int)s4.z;
            p = atomicAdd(&bcnt[(d4.w >> BSH) << 4], 1);
            if (p < BCAP) bslot[((long)(d4.w >> BSH) << 10) + p] =
                ((unsigned int)(d4.w & (BNODES - 1)) << 16) | (unsigned int)s4.w;
        }
        for (int i = (E4 << 2) + hid; i < E; i += hthreads) {
            int d = edst[i];
            int p = atomicAdd(&bcnt[(d >> BSH) << 4], 1);
            if (p < BCAP) bslot[((long)(d >> BSH) << 10) + p] =
                ((unsigned int)(d & (BNODES - 1)) << 16) | (unsigned int)esrc[i];
        }
        return;
    }
    // ---- gemm1 part ----
    const int w = tid >> 6, lane = tid & 63;
    const int quad = lane >> 4, col = lane & 15;

    short8 wf[4][4];
#pragma unroll
    for (int kk = 0; kk < 4; kk++)
#pragma unroll
        for (int j = 0; j < 4; j++)
            wf[kk][j] = ((const short8*)w1f)[(kk * 16 + w * 4 + j) * 64 + lane];
    float4 bias = make_float4(0.f, 0.f, 0.f, 0.f);
    if (w >= 2) bias = *(const float4*)(b1 + (w - 2) * 64 + col * 4);
    unsigned short* Yhalf = (w < 2) ? Ys : Yd;
    const int cb = (w & 1) * 64;

    for (int t = blockIdx.x; t < nTiles; t += nb1) {
        const int n0 = t * 16;
        const int nr = n0 + col;                 // N % 16 == 0
        const float* xrow = x + (long)nr * D;
        float4 f[8];
#pragma unroll
        for (int kk = 0; kk < 4; kk++) {
            f[kk * 2]     = *(const float4*)(xrow + kk * 32 + quad * 8);
            f[kk * 2 + 1] = *(const float4*)(xrow + kk * 32 + quad * 8 + 4);
        }
        floatx4 acc[4];
#pragma unroll
        for (int j = 0; j < 4; j++)
#pragma unroll
            for (int q = 0; q < 4; q++) acc[j][q] = 0.f;
#pragma unroll
        for (int kk = 0; kk < 4; kk++) {
            union { short8 s; unsigned int u[4]; } au;
            asm("v_cvt_pk_bf16_f32 %0, %1, %2" : "=v"(au.u[0]) : "v"(f[kk*2].x),   "v"(f[kk*2].y));
            asm("v_cvt_pk_bf16_f32 %0, %1, %2" : "=v"(au.u[1]) : "v"(f[kk*2].z),   "v"(f[kk*2].w));
            asm("v_cvt_pk_bf16_f32 %0, %1, %2" : "=v"(au.u[2]) : "v"(f[kk*2+1].x), "v"(f[kk*2+1].y));
            asm("v_cvt_pk_bf16_f32 %0, %1, %2" : "=v"(au.u[3]) : "v"(f[kk*2+1].z), "v"(f[kk*2+1].w));
#pragma unroll
            for (int j = 0; j < 4; j++)
                acc[j] = __builtin_amdgcn_mfma_f32_16x16x32_bf16(au.s, wf[kk][j], acc[j], 0, 0, 0);
        }
#pragma unroll
        for (int r = 0; r < 4; r++) {
            int n = n0 + quad * 4 + r;
            ushort4 o;
            o.x = f2bf(acc[0][r] + bias.x);
            o.y = f2bf(acc[1][r] + bias.y);
            o.z = f2bf(acc[2][r] + bias.z);
            o.w = f2bf(acc[3][r] + bias.w);
            *(ushort4*)(Yhalf + (long)n * D + cb + col * 4) = o;
        }
    }
}

// D3: one block (4 waves) per bucket of 64 dst nodes. Stage Yd rows (16KB) + fp32
// accumulator (32KB) in LDS; waves stream packed edges (coalesced 64-wide slot load
// + shfl broadcast), gather Ys[src] rows (256B, L3-hot), relu, ds_add_f32 (fire-and-
// forget, never blocks). Epilogue: convert + write contiguous agg rows.
__global__ __launch_bounds__(256, 3) void k_agg(
    const unsigned short* __restrict__ Ys,
    const unsigned short* __restrict__ Yd,
    const int* __restrict__ bcnt,
    const unsigned int* __restrict__ bslot,
    unsigned short* __restrict__ aggb, int N)
{
    __shared__ float acc[BNODES * D];               // 32 KB
    __shared__ unsigned int ydl[BNODES * (D / 2)];  // 16 KB (bf16x2 per uint)
    const int tid = threadIdx.x, w = tid >> 6, lane = tid & 63;
    const int b = blockIdx.x;
    const int nb0 = b << BSH;
    int nd = N - nb0; if (nd > BNODES) nd = BNODES;

#pragma unroll
    for (int i = 0; i < (BNODES * D) / 256; i++)    // 32 iters
        acc[tid + i * 256] = 0.f;
    for (int i = tid; i < nd * (D / 2); i += 256) {
        int row = i >> 6, colu = i & 63;
        ydl[i] = *(const unsigned int*)(Yd + (long)(nb0 + row) * D + colu * 2);
    }
    __syncthreads();

    int bc = bcnt[b << 4]; if (bc > BCAP) bc = BCAP;
    const unsigned int* slots = bslot + ((long)b << 10);
    const unsigned short* ysl = Ys + lane * 2;

    for (int c0 = w << 6; c0 < bc; c0 += 256) {     // wave-strided 64-slot chunks
        int nj = bc - c0; if (nj > 64) nj = 64;
        unsigned int myp = (lane < nj) ? slots[c0 + lane] : 0u;
        int j = 0;
        for (; j + 4 <= nj; j += 4) {
            unsigned int p0 = __shfl(myp, j, 64);
            unsigned int p1 = __shfl(myp, j + 1, 64);
            unsigned int p2 = __shfl(myp, j + 2, 64);
            unsigned int p3 = __shfl(myp, j + 3, 64);
            unsigned int u0 = *(const unsigned int*)(ysl + (long)(p0 & 0xffffu) * D);
            unsigned int u1 = *(const unsigned int*)(ysl + (long)(p1 & 0xffffu) * D);
            unsigned int u2 = *(const unsigned int*)(ysl + (long)(p2 & 0xffffu) * D);
            unsigned int u3 = *(const unsigned int*)(ysl + (long)(p3 & 0xffffu) * D);
            int d0 = p0 >> 16, d1 = p1 >> 16, d2 = p2 >> 16, d3 = p3 >> 16;
            unsigned int y0 = ydl[(d0 << 6) + lane];
            unsigned int y1 = ydl[(d1 << 6) + lane];
            unsigned int y2 = ydl[(d2 << 6) + lane];
            unsigned int y3 = ydl[(d3 << 6) + lane];
            atomicAdd(&acc[(d0 << 7) + lane * 2],     fmaxf(bflo(u0) + bflo(y0), 0.f));
            atomicAdd(&acc[(d0 << 7) + lane * 2 + 1], fmaxf(bfhi(u0) + bfhi(y0), 0.f));
            atomicAdd(&acc[(d1 << 7) + lane * 2],     fmaxf(bflo(u1) + bflo(y1), 0.f));
            atomicAdd(&acc[(d1 << 7) + lane * 2 + 1], fmaxf(bfhi(u1) + bfhi(y1), 0.f));
            atomicAdd(&acc[(d2 << 7) + lane * 2],     fmaxf(bflo(u2) + bflo(y2), 0.f));
            atomicAdd(&acc[(d2 << 7) + lane * 2 + 1], fmaxf(bfhi(u2) + bfhi(y2), 0.f));
            atomicAdd(&acc[(d3 << 7) + lane * 2],     fmaxf(bflo(u3) + bflo(y3), 0.f));
            atomicAdd(&acc[(d3 << 7) + lane * 2 + 1], fmaxf(bfhi(u3) + bfhi(y3), 0.f));
        }
        for (; j < nj; j++) {
            unsigned int p0 = __shfl(myp, j, 64);
            unsigned int u0 = *(const unsigned int*)(ysl + (long)(p0 & 0xffffu) * D);
            int d0 = p0 >> 16;
            unsigned int y0 = ydl[(d0 << 6) + lane];
            atomicAdd(&acc[(d0 << 7) + lane * 2],     fmaxf(bflo(u0) + bflo(y0), 0.f));
            atomicAdd(&acc[(d0 << 7) + lane * 2 + 1], fmaxf(bfhi(u0) + bfhi(y0), 0.f));
        }
    }
    __syncthreads();
    for (int i = tid; i < nd * (D / 2); i += 256) {
        int row = i >> 6, colu = i & 63;
        float a0 = acc[(row << 7) + colu * 2];
        float a1 = acc[(row << 7) + colu * 2 + 1];
        unsigned int o = (unsigned int)f2bf(a0) | ((unsigned int)f2bf(a1) << 16);
        *(unsigned int*)(aggb + (long)(nb0 + row) * D + colu * 2) = o;
    }
}

// D4: out = x + relu([x;agg]@W2 + b2). M=N, K=256, Nout=128. A-operand for K<128
// converted from fp32 x in-register. Block = 4 waves; wave w owns out-cols [w*32,w*32+32).
// Frag c of wave w holds actual col w*32 + 2*(lane&15) + c  ->  8B float2 stores.
__global__ __launch_bounds__(256, 4) void k_gemm2(
    const float* __restrict__ x,
    const unsigned short* __restrict__ aggb,
    const unsigned short* __restrict__ w2f,
    const float* __restrict__ b2,
    float* __restrict__ out,
    int N, int nTiles)
{
    const int tid = threadIdx.x, w = tid >> 6, lane = tid & 63;
    const int quad = lane >> 4, col = lane & 15;

    short8 wf[8][2];
#pragma unroll
    for (int kk = 0; kk < 8; kk++)
#pragma unroll
        for (int c = 0; c < 2; c++)
            wf[kk][c] = ((const short8*)w2f)[(kk * 8 + w * 2 + c) * 64 + lane];
    float2 bias = *(const float2*)(b2 + w * 32 + col * 2);

    for (int t = blockIdx.x; t < nTiles; t += gridDim.x) {
        const int n0 = t * 16;
        const int nr = n0 + col;                 // N % 16 == 0
        const float* xrow = x + (long)nr * D;
        float4 f[8];
        short8 ag[4];
#pragma unroll
        for (int kk = 0; kk < 4; kk++) {
            f[kk * 2]     = *(const float4*)(xrow + kk * 32 + quad * 8);
            f[kk * 2 + 1] = *(const float4*)(xrow + kk * 32 + quad * 8 + 4);
        }
#pragma unroll
        for (int kk = 0; kk < 4; kk++)
            ag[kk] = *(const short8*)(aggb + (long)nr * D + kk * 32 + quad * 8);
        floatx4 acc[2];
#pragma unroll
        for (int c = 0; c < 2; c++)
#pragma unroll
            for (int q = 0; q < 4; q++) acc[c][q] = 0.f;
#pragma unroll
        for (int kk = 0; kk < 4; kk++) {
            union { short8 s; unsigned int u[4]; } au;
            asm("v_cvt_pk_bf16_f32 %0, %1, %2" : "=v"(au.u[0]) : "v"(f[kk*2].x),   "v"(f[kk*2].y));
            asm("v_cvt_pk_bf16_f32 %0, %1, %2" : "=v"(au.u[1]) : "v"(f[kk*2].z),   "v"(f[kk*2].w));
            asm("v_cvt_pk_bf16_f32 %0, %1, %2" : "=v"(au.u[2]) : "v"(f[kk*2+1].x), "v"(f[kk*2+1].y));
            asm("v_cvt_pk_bf16_f32 %0, %1, %2" : "=v"(au.u[3]) : "v"(f[kk*2+1].z), "v"(f[kk*2+1].w));
            acc[0] = __builtin_amdgcn_mfma_f32_16x16x32_bf16(au.s, wf[kk][0], acc[0], 0, 0, 0);
            acc[1] = __builtin_amdgcn_mfma_f32_16x16x32_bf16(au.s, wf[kk][1], acc[1], 0, 0, 0);
        }
#pragma unroll
        for (int kk = 4; kk < 8; kk++) {
            acc[0] = __builtin_amdgcn_mfma_f32_16x16x32_bf16(ag[kk - 4], wf[kk][0], acc[0], 0, 0, 0);
            acc[1] = __builtin_amdgcn_mfma_f32_16x16x32_bf16(ag[kk - 4], wf[kk][1], acc[1], 0, 0, 0);
        }
#pragma unroll
        for (int r = 0; r < 4; r++) {
            int n = n0 + quad * 4 + r;
            long off = (long)n * D + w * 32 + col * 2;
            float2 xr = *(const float2*)(x + off);
            float v0 = fmaxf(acc[0][r] + bias.x, 0.f);
            float v1 = fmaxf(acc[1][r] + bias.y, 0.f);
            *(float2*)(out + off) = make_float2(xr.x + v0, xr.y + v1);
        }
    }
}

extern "C" void kernel_launch(void* const* d_in, const int* in_sizes, int n_in,
                              void* d_out, int out_size, void* d_ws, size_t ws_size,
                              hipStream_t stream)
{
    const float* x   = (const float*)d_in[0];
    const int* esrc  = (const int*)d_in[1];
    const int* edst  = (const int*)d_in[2];
    const float* W1  = (const float*)d_in[3];
    const float* b1  = (const float*)d_in[4];
    const float* W2  = (const float*)d_in[5];
    const float* b2  = (const float*)d_in[6];
    float* out = (float*)d_out;

    const int ND = in_sizes[0];     // N*D
    const int N  = ND / D;          // 50000
    const int E  = in_sizes[1];     // 600000

    // workspace carve-out (256B-aligned chunks), ~45 MB
    char* p = (char*)d_ws;
    auto alloc = [&](size_t bytes) { char* r = p; p += (bytes + 255) & ~(size_t)255; return r; };
    unsigned short* Ys   = (unsigned short*)alloc((size_t)ND * 2);
    unsigned short* Yd   = (unsigned short*)alloc((size_t)ND * 2);
    unsigned short* aggb = (unsigned short*)alloc((size_t)ND * 2);
    unsigned short* w1f  = (unsigned short*)alloc(32768 * 2);
    unsigned short* w2f  = (unsigned short*)alloc(32768 * 2);

    const int NB = (N + BNODES - 1) >> BSH;          // 782 buckets
    int* bcnt          = (int*)alloc((size_t)NB * 16 * 4);      // padded: 1 counter / 64B
    unsigned int* bslot = (unsigned int*)alloc((size_t)NB * BCAP * 4);

    const int nTiles = N / 16;              // 3125 (N % 16 == 0)
    const int nb1 = (nTiles + 2) / 3;       // 1042: each gemm block does <=3 tiles
    const int nbA = ((E >> 2) + 255) / 256; // 586: one int4 edge-group per thread

    k_pre<<<256, 256, 0, stream>>>(W1, W2, w1f, w2f, bcnt, N);
    k_fat1<<<nb1 + nbA, 256, 0, stream>>>(x, w1f, b1, Ys, Yd, esrc, edst, bcnt, bslot,
                                          N, nTiles, nb1, E);
    k_agg<<<NB, 256, 0, stream>>>(Ys, Yd, bcnt, bslot, aggb, N);
    k_gemm2<<<nb1, 256, 0, stream>>>(x, aggb, w2f, b2, out, N, nTiles);
}

// Round 10
// 185.624 us; speedup vs baseline: 3.6807x; 3.6807x over previous
//
#include <hip/hip_runtime.h>
#include <stdint.h>

// RelationalMSG decomposed, 4 dispatches:
//   D1 k_pre:   zero bucket counters + convert W1/W2 -> MFMA B-frag layout (bf16)
//   D2 k_fat1:  block-split: gemm1 (Ys = x@W1a, Yd = x@W1b + b1, x cvt in-reg)
//               || bucket edge-binning: b=dst>>6; p=bcnt[b]++ (PADDED hot counter);
//               bslot[b*1024+p] = (dst&63)<<16 | src. 782 line-resident counters,
//               adjacent slot stores (validated r9: fat1 left the top-5).
//   D3 k_agg:   one 512-thread block per bucket: stage slots in LDS, counting-sort
//               by 6-bit local dst IN LDS (~1.5K LDS atomics on 64 counters), then
//               8 waves x 8 nodes each run the r8-proven gather loop: register
//               scalar accumulation, 8 independent 256B Ys row loads in flight.
//               NO per-element LDS atomics (r9 lesson: 76.8M LDS RMWs = 531us).
//   D4 k_gemm2: out = x + relu([x;agg]@W2 + b2)  (x cvt in-reg; no xb buffer)
// N=50000 (16 | N), E=600000, D=128. Edges/bucket ~Poisson(768), BCAP=1024 is
// 9 sigma (clamped anyway; cannot corrupt memory).
// Lessons: no grid.sync (~50us/barrier); device atomics resolve at the memory-side
// slice (sharding counters near-null, r8); scattered per-dst appends ~60us (r7/r8);
// HOT bucket counters are cheap (r9); per-element LDS atomics are catastrophic (r9).

typedef __attribute__((ext_vector_type(8))) short short8;   // 8 bf16 (MFMA A/B frag)
typedef __attribute__((ext_vector_type(4))) float floatx4;  // MFMA C/D frag

#define D 128
#define BSH 6              // 64 nodes per bucket
#define BNODES 64
#define BCAP 1024

static __device__ __forceinline__ unsigned short f2bf(float f) {
    union { float f; unsigned int u; } v; v.f = f;
    unsigned int r = (v.u + 0x7fffu + ((v.u >> 16) & 1u)) >> 16; // RNE
    return (unsigned short)r;
}
static __device__ __forceinline__ float bflo(unsigned int u) {
    union { unsigned int u; float f; } v; v.u = u << 16; return v.f;
}
static __device__ __forceinline__ float bfhi(unsigned int u) {
    union { unsigned int u; float f; } v; v.u = u & 0xffff0000u; return v.f;
}

// B-fragment layouts (column-PERMUTED so each lane's frags hold ADJACENT output cols):
// w1f (gemm1, K=128, 256 out cols): frag[(kk*16+ct)*64+lane][j] =
//      B1[kk*32+(lane>>4)*8+j][ (ct>>2)*64 + 4*(lane&15) + (ct&3) ]
//   B1[k][c] = c<128 ? W1[k][c] : W1[128+k][c-128]   (W1 is [256][128])
// w2f (gemm2, K=256, 128 out cols): frag[(kk*8+ct)*64+lane][j] =
//      W2[kk*32+(lane>>4)*8+j][ (ct>>1)*32 + 2*(lane&15) + (ct&1) ]
// Also zeroes the padded bucket counters (NB*16 ints).
__global__ void k_pre(const float* __restrict__ W1, const float* __restrict__ W2,
                      unsigned short* __restrict__ w1f, unsigned short* __restrict__ w2f,
                      int* __restrict__ bcnt, int N) {
    int gid = blockIdx.x * blockDim.x + threadIdx.x; // 65536 threads
    int nb16 = (((N + BNODES - 1) >> BSH) << 4);
    if (gid < nb16) bcnt[gid] = 0;
    if (gid < 32768) {
        int tid = gid;
        int j = tid & 7, lane = (tid >> 3) & 63, ct = (tid >> 9) & 15, kk = tid >> 13;
        int k = kk * 32 + (lane >> 4) * 8 + j;
        int c = ((ct >> 2) << 6) + ((lane & 15) << 2) + (ct & 3);
        float v = (c < 128) ? W1[k * 128 + c] : W1[(128 + k) * 128 + (c - 128)];
        w1f[tid] = f2bf(v);
    } else if (gid < 65536) {
        int tid = gid - 32768;
        int j = tid & 7, lane = (tid >> 3) & 63, ct = (tid >> 9) & 7, kk = tid >> 12;
        int k = kk * 32 + (lane >> 4) * 8 + j;
        int c = ((ct >> 1) << 5) + ((lane & 15) << 1) + (ct & 1);
        w2f[tid] = f2bf(W2[k * 128 + c]);
    }
}

// D2: blocks [0,nb1) = gemm1 (M=N, K=128, Nout=256); blocks [nb1,grid) = bucket
// edge-binning. gemm1: block = 4 waves; wave w owns out-cols [w*64,w*64+64).
// Frag j of wave w holds actual col w*64 + 4*(lane&15) + j  ->  8B ushort4 stores.
__global__ __launch_bounds__(256, 4) void k_fat1(
    const float* __restrict__ x,
    const unsigned short* __restrict__ w1f,
    const float* __restrict__ b1,
    unsigned short* __restrict__ Ys,
    unsigned short* __restrict__ Yd,
    const int* __restrict__ esrc,
    const int* __restrict__ edst,
    int* __restrict__ bcnt,
    unsigned int* __restrict__ bslot,
    int N, int nTiles, int nb1, int E)
{
    const int tid = threadIdx.x;
    if ((int)blockIdx.x >= nb1) {
        // ---- bucket edge-binning (one int4 edge-group per thread) ----
        const int hthreads = (gridDim.x - nb1) * 256;
        const int hid = (blockIdx.x - nb1) * 256 + tid;
        const int E4 = E >> 2;
        for (int i = hid; i < E4; i += hthreads) {
            int4 s4 = ((const int4*)esrc)[i];
            int4 d4 = ((const int4*)edst)[i];
            int p;
            p = atomicAdd(&bcnt[(d4.x >> BSH) << 4], 1);
            if (p < BCAP) bslot[((long)(d4.x >> BSH) << 10) + p] =
                ((unsigned int)(d4.x & (BNODES - 1)) << 16) | (unsigned int)s4.x;
            p = atomicAdd(&bcnt[(d4.y >> BSH) << 4], 1);
            if (p < BCAP) bslot[((long)(d4.y >> BSH) << 10) + p] =
                ((unsigned int)(d4.y & (BNODES - 1)) << 16) | (unsigned int)s4.y;
            p = atomicAdd(&bcnt[(d4.z >> BSH) << 4], 1);
            if (p < BCAP) bslot[((long)(d4.z >> BSH) << 10) + p] =
                ((unsigned int)(d4.z & (BNODES - 1)) << 16) | (unsigned int)s4.z;
            p = atomicAdd(&bcnt[(d4.w >> BSH) << 4], 1);
            if (p < BCAP) bslot[((long)(d4.w >> BSH) << 10) + p] =
                ((unsigned int)(d4.w & (BNODES - 1)) << 16) | (unsigned int)s4.w;
        }
        for (int i = (E4 << 2) + hid; i < E; i += hthreads) {
            int d = edst[i];
            int p = atomicAdd(&bcnt[(d >> BSH) << 4], 1);
            if (p < BCAP) bslot[((long)(d >> BSH) << 10) + p] =
                ((unsigned int)(d & (BNODES - 1)) << 16) | (unsigned int)esrc[i];
        }
        return;
    }
    // ---- gemm1 part ----
    const int w = tid >> 6, lane = tid & 63;
    const int quad = lane >> 4, col = lane & 15;

    short8 wf[4][4];
#pragma unroll
    for (int kk = 0; kk < 4; kk++)
#pragma unroll
        for (int j = 0; j < 4; j++)
            wf[kk][j] = ((const short8*)w1f)[(kk * 16 + w * 4 + j) * 64 + lane];
    float4 bias = make_float4(0.f, 0.f, 0.f, 0.f);
    if (w >= 2) bias = *(const float4*)(b1 + (w - 2) * 64 + col * 4);
    unsigned short* Yhalf = (w < 2) ? Ys : Yd;
    const int cb = (w & 1) * 64;

    for (int t = blockIdx.x; t < nTiles; t += nb1) {
        const int n0 = t * 16;
        const int nr = n0 + col;                 // N % 16 == 0
        const float* xrow = x + (long)nr * D;
        float4 f[8];
#pragma unroll
        for (int kk = 0; kk < 4; kk++) {
            f[kk * 2]     = *(const float4*)(xrow + kk * 32 + quad * 8);
            f[kk * 2 + 1] = *(const float4*)(xrow + kk * 32 + quad * 8 + 4);
        }
        floatx4 acc[4];
#pragma unroll
        for (int j = 0; j < 4; j++)
#pragma unroll
            for (int q = 0; q < 4; q++) acc[j][q] = 0.f;
#pragma unroll
        for (int kk = 0; kk < 4; kk++) {
            union { short8 s; unsigned int u[4]; } au;
            asm("v_cvt_pk_bf16_f32 %0, %1, %2" : "=v"(au.u[0]) : "v"(f[kk*2].x),   "v"(f[kk*2].y));
            asm("v_cvt_pk_bf16_f32 %0, %1, %2" : "=v"(au.u[1]) : "v"(f[kk*2].z),   "v"(f[kk*2].w));
            asm("v_cvt_pk_bf16_f32 %0, %1, %2" : "=v"(au.u[2]) : "v"(f[kk*2+1].x), "v"(f[kk*2+1].y));
            asm("v_cvt_pk_bf16_f32 %0, %1, %2" : "=v"(au.u[3]) : "v"(f[kk*2+1].z), "v"(f[kk*2+1].w));
#pragma unroll
            for (int j = 0; j < 4; j++)
                acc[j] = __builtin_amdgcn_mfma_f32_16x16x32_bf16(au.s, wf[kk][j], acc[j], 0, 0, 0);
        }
#pragma unroll
        for (int r = 0; r < 4; r++) {
            int n = n0 + quad * 4 + r;
            ushort4 o;
            o.x = f2bf(acc[0][r] + bias.x);
            o.y = f2bf(acc[1][r] + bias.y);
            o.z = f2bf(acc[2][r] + bias.z);
            o.w = f2bf(acc[3][r] + bias.w);
            *(ushort4*)(Yhalf + (long)n * D + cb + col * 4) = o;
        }
    }
}

// D3: one 512-thread block per bucket of 64 dst nodes.
// Phase A: stage packed slots into LDS, counting-sort by local dst (64 LDS counters
// + one 64-lane shfl scan). Phase B: 8 waves x 8 nodes; per node the r8-proven
// gather loop (register scalars, 8 independent 256B Ys row reads in flight, src
// indices broadcast-read from the sorted LDS list). Contiguous agg row writes.
__global__ __launch_bounds__(512, 2) void k_agg(
    const unsigned short* __restrict__ Ys,
    const unsigned short* __restrict__ Yd,
    const int* __restrict__ bcnt,
    const unsigned int* __restrict__ bslot,
    unsigned short* __restrict__ aggb, int N)
{
    __shared__ unsigned int eb[BCAP];          // 4 KB
    __shared__ unsigned short sorted[BCAP];    // 2 KB
    __shared__ int cnt64[BNODES], start64[BNODES], cur64[BNODES];
    const int tid = threadIdx.x, w = tid >> 6, lane = tid & 63;
    const int b = blockIdx.x, nb0 = b << BSH;
    int nd = N - nb0; if (nd > BNODES) nd = BNODES;
    int bc = bcnt[b << 4]; if (bc > BCAP) bc = BCAP;

    if (tid < BNODES) cnt64[tid] = 0;
    __syncthreads();
    for (int i = tid; i < bc; i += 512) {
        unsigned int e = bslot[((long)b << 10) + i];
        eb[i] = e;
        atomicAdd(&cnt64[e >> 16], 1);
    }
    __syncthreads();
    if (tid < 64) {
        int c = cnt64[tid];
        int incl = c;
#pragma unroll
        for (int off = 1; off < 64; off <<= 1) {
            int t = __shfl_up(incl, off, 64);
            if (lane >= off) incl += t;
        }
        start64[tid] = incl - c;
        cur64[tid] = incl - c;
    }
    __syncthreads();
    for (int i = tid; i < bc; i += 512) {
        unsigned int e = eb[i];
        int p = atomicAdd(&cur64[e >> 16], 1);
        sorted[p] = (unsigned short)(e & 0xffffu);
    }
    __syncthreads();

    const unsigned short* ysl = Ys + lane * 2;
#pragma unroll
    for (int k = 0; k < 8; k++) {
        int ln = w * 8 + k;
        if (ln >= nd) break;
        const int node = nb0 + ln;
        const int deg = cnt64[ln], base = start64[ln];
        unsigned int ydu = *(const unsigned int*)(Yd + (long)node * D + lane * 2);
        float yd0 = bflo(ydu), yd1 = bfhi(ydu);
        float a0 = 0.f, a1 = 0.f;
        int e = 0;
        for (; e + 8 <= deg; e += 8) {
            int s[8]; unsigned int u[8];
#pragma unroll
            for (int q = 0; q < 8; q++) s[q] = sorted[base + e + q];
#pragma unroll
            for (int q = 0; q < 8; q++) u[q] = *(const unsigned int*)(ysl + (long)s[q] * D);
#pragma unroll
            for (int q = 0; q < 8; q++) {
                a0 += fmaxf(bflo(u[q]) + yd0, 0.f);
                a1 += fmaxf(bfhi(u[q]) + yd1, 0.f);
            }
        }
        for (; e + 4 <= deg; e += 4) {
            int s[4]; unsigned int u[4];
#pragma unroll
            for (int q = 0; q < 4; q++) s[q] = sorted[base + e + q];
#pragma unroll
            for (int q = 0; q < 4; q++) u[q] = *(const unsigned int*)(ysl + (long)s[q] * D);
#pragma unroll
            for (int q = 0; q < 4; q++) {
                a0 += fmaxf(bflo(u[q]) + yd0, 0.f);
                a1 += fmaxf(bfhi(u[q]) + yd1, 0.f);
            }
        }
        for (; e < deg; e++) {
            unsigned int u0 = *(const unsigned int*)(ysl + (long)sorted[base + e] * D);
            a0 += fmaxf(bflo(u0) + yd0, 0.f);
            a1 += fmaxf(bfhi(u0) + yd1, 0.f);
        }
        unsigned int o = (unsigned int)f2bf(a0) | ((unsigned int)f2bf(a1) << 16);
        *(unsigned int*)(aggb + (long)node * D + lane * 2) = o;
    }
}

// D4: out = x + relu([x;agg]@W2 + b2). M=N, K=256, Nout=128. A-operand for K<128
// converted from fp32 x in-register. Block = 4 waves; wave w owns out-cols [w*32,w*32+32).
// Frag c of wave w holds actual col w*32 + 2*(lane&15) + c  ->  8B float2 stores.
__global__ __launch_bounds__(256, 4) void k_gemm2(
    const float* __restrict__ x,
    const unsigned short* __restrict__ aggb,
    const unsigned short* __restrict__ w2f,
    const float* __restrict__ b2,
    float* __restrict__ out,
    int N, int nTiles)
{
    const int tid = threadIdx.x, w = tid >> 6, lane = tid & 63;
    const int quad = lane >> 4, col = lane & 15;

    short8 wf[8][2];
#pragma unroll
    for (int kk = 0; kk < 8; kk++)
#pragma unroll
        for (int c = 0; c < 2; c++)
            wf[kk][c] = ((const short8*)w2f)[(kk * 8 + w * 2 + c) * 64 + lane];
    float2 bias = *(const float2*)(b2 + w * 32 + col * 2);

    for (int t = blockIdx.x; t < nTiles; t += gridDim.x) {
        const int n0 = t * 16;
        const int nr = n0 + col;                 // N % 16 == 0
        const float* xrow = x + (long)nr * D;
        float4 f[8];
        short8 ag[4];
#pragma unroll
        for (int kk = 0; kk < 4; kk++) {
            f[kk * 2]     = *(const float4*)(xrow + kk * 32 + quad * 8);
            f[kk * 2 + 1] = *(const float4*)(xrow + kk * 32 + quad * 8 + 4);
        }
#pragma unroll
        for (int kk = 0; kk < 4; kk++)
            ag[kk] = *(const short8*)(aggb + (long)nr * D + kk * 32 + quad * 8);
        floatx4 acc[2];
#pragma unroll
        for (int c = 0; c < 2; c++)
#pragma unroll
            for (int q = 0; q < 4; q++) acc[c][q] = 0.f;
#pragma unroll
        for (int kk = 0; kk < 4; kk++) {
            union { short8 s; unsigned int u[4]; } au;
            asm("v_cvt_pk_bf16_f32 %0, %1, %2" : "=v"(au.u[0]) : "v"(f[kk*2].x),   "v"(f[kk*2].y));
            asm("v_cvt_pk_bf16_f32 %0, %1, %2" : "=v"(au.u[1]) : "v"(f[kk*2].z),   "v"(f[kk*2].w));
            asm("v_cvt_pk_bf16_f32 %0, %1, %2" : "=v"(au.u[2]) : "v"(f[kk*2+1].x), "v"(f[kk*2+1].y));
            asm("v_cvt_pk_bf16_f32 %0, %1, %2" : "=v"(au.u[3]) : "v"(f[kk*2+1].z), "v"(f[kk*2+1].w));
            acc[0] = __builtin_amdgcn_mfma_f32_16x16x32_bf16(au.s, wf[kk][0], acc[0], 0, 0, 0);
            acc[1] = __builtin_amdgcn_mfma_f32_16x16x32_bf16(au.s, wf[kk][1], acc[1], 0, 0, 0);
        }
#pragma unroll
        for (int kk = 4; kk < 8; kk++) {
            acc[0] = __builtin_amdgcn_mfma_f32_16x16x32_bf16(ag[kk - 4], wf[kk][0], acc[0], 0, 0, 0);
            acc[1] = __builtin_amdgcn_mfma_f32_16x16x32_bf16(ag[kk - 4], wf[kk][1], acc[1], 0, 0, 0);
        }
#pragma unroll
        for (int r = 0; r < 4; r++) {
            int n = n0 + quad * 4 + r;
            long off = (long)n * D + w * 32 + col * 2;
            float2 xr = *(const float2*)(x + off);
            float v0 = fmaxf(acc[0][r] + bias.x, 0.f);
            float v1 = fmaxf(acc[1][r] + bias.y, 0.f);
            *(float2*)(out + off) = make_float2(xr.x + v0, xr.y + v1);
        }
    }
}

extern "C" void kernel_launch(void* const* d_in, const int* in_sizes, int n_in,
                              void* d_out, int out_size, void* d_ws, size_t ws_size,
                              hipStream_t stream)
{
    const float* x   = (const float*)d_in[0];
    const int* esrc  = (const int*)d_in[1];
    const int* edst  = (const int*)d_in[2];
    const float* W1  = (const float*)d_in[3];
    const float* b1  = (const float*)d_in[4];
    const float* W2  = (const float*)d_in[5];
    const float* b2  = (const float*)d_in[6];
    float* out = (float*)d_out;

    const int ND = in_sizes[0];     // N*D
    const int N  = ND / D;          // 50000
    const int E  = in_sizes[1];     // 600000

    // workspace carve-out (256B-aligned chunks), ~45 MB
    char* p = (char*)d_ws;
    auto alloc = [&](size_t bytes) { char* r = p; p += (bytes + 255) & ~(size_t)255; return r; };
    unsigned short* Ys   = (unsigned short*)alloc((size_t)ND * 2);
    unsigned short* Yd   = (unsigned short*)alloc((size_t)ND * 2);
    unsigned short* aggb = (unsigned short*)alloc((size_t)ND * 2);
    unsigned short* w1f  = (unsigned short*)alloc(32768 * 2);
    unsigned short* w2f  = (unsigned short*)alloc(32768 * 2);

    const int NB = (N + BNODES - 1) >> BSH;          // 782 buckets
    int* bcnt           = (int*)alloc((size_t)NB * 16 * 4);     // padded: 1 counter / 64B
    unsigned int* bslot = (unsigned int*)alloc((size_t)NB * BCAP * 4);

    const int nTiles = N / 16;              // 3125 (N % 16 == 0)
    const int nb1 = (nTiles + 2) / 3;       // 1042: each gemm block does <=3 tiles
    const int nbA = ((E >> 2) + 255) / 256; // 586: one int4 edge-group per thread

    k_pre<<<256, 256, 0, stream>>>(W1, W2, w1f, w2f, bcnt, N);
    k_fat1<<<nb1 + nbA, 256, 0, stream>>>(x, w1f, b1, Ys, Yd, esrc, edst, bcnt, bslot,
                                          N, nTiles, nb1, E);
    k_agg<<<NB, 512, 0, stream>>>(Ys, Yd, bcnt, bslot, aggb, N);
    k_gemm2<<<nb1, 256, 0, stream>>>(x, aggb, w2f, b2, out, N, nTiles);
}

// Round 11
// 184.093 us; speedup vs baseline: 3.7113x; 1.0083x over previous
//
#include <hip/hip_runtime.h>
#include <stdint.h>

// RelationalMSG decomposed, 4 dispatches:
//   D1 k_pre:   zero bucket counters + convert W1/W2 -> MFMA B-frag layout (bf16)
//   D2 k_fat1:  blocks 0..63 = two-phase binning sorters (LDS histogram ->
//               ONE global atomicAdd per (block,bucket) run reservation -> LDS-cursor
//               scatter into contiguous runs). 50K device atomics instead of 600K
//               (r3-r10 invariant: 600K device atomics = 35-40us at ~60ns/op
//               REGARDLESS of locality -> count is the only lever).
//               blocks 64.. = gemm1 (Ys = x@W1a, Yd = x@W1b + b1, x cvt in-reg).
//   D3 k_agg:   one 512-thread block per bucket: stage slots in LDS, counting-sort
//               by 6-bit local dst in LDS, then 8 waves x 8 nodes run the register-
//               scalar gather loop (8 independent 256B Ys row loads in flight).
//   D4 k_gemm2: out = x + relu([x;agg]@W2 + b2)  (x cvt in-reg; no xb buffer)
// N=50000 (16 | N), E=600000, D=128. Edges/bucket ~Poisson(768), BCAP=1024 is
// 9 sigma (write-guarded anyway; cannot corrupt memory).
// Lessons: no grid.sync (~50us/barrier); device-atomic THROUGHPUT ~60ns/op is the
// binning floor (r3-r10); per-element LDS atomics catastrophic (r9, 531us);
// LDS counting-sort + register gather is the right agg structure (r10).

typedef __attribute__((ext_vector_type(8))) short short8;   // 8 bf16 (MFMA A/B frag)
typedef __attribute__((ext_vector_type(4))) float floatx4;  // MFMA C/D frag

#define D 128
#define BSH 6              // 64 nodes per bucket
#define BNODES 64
#define BCAP 1024
#define NSORT 64           // sorter blocks (50K reservation atomics total)

static __device__ __forceinline__ unsigned short f2bf(float f) {
    union { float f; unsigned int u; } v; v.f = f;
    unsigned int r = (v.u + 0x7fffu + ((v.u >> 16) & 1u)) >> 16; // RNE
    return (unsigned short)r;
}
static __device__ __forceinline__ float bflo(unsigned int u) {
    union { unsigned int u; float f; } v; v.u = u << 16; return v.f;
}
static __device__ __forceinline__ float bfhi(unsigned int u) {
    union { unsigned int u; float f; } v; v.u = u & 0xffff0000u; return v.f;
}

// B-fragment layouts (column-PERMUTED so each lane's frags hold ADJACENT output cols):
// w1f (gemm1, K=128, 256 out cols): frag[(kk*16+ct)*64+lane][j] =
//      B1[kk*32+(lane>>4)*8+j][ (ct>>2)*64 + 4*(lane&15) + (ct&3) ]
//   B1[k][c] = c<128 ? W1[k][c] : W1[128+k][c-128]   (W1 is [256][128])
// w2f (gemm2, K=256, 128 out cols): frag[(kk*8+ct)*64+lane][j] =
//      W2[kk*32+(lane>>4)*8+j][ (ct>>1)*32 + 2*(lane&15) + (ct&1) ]
// Also zeroes the padded bucket counters (NB*16 ints).
__global__ void k_pre(const float* __restrict__ W1, const float* __restrict__ W2,
                      unsigned short* __restrict__ w1f, unsigned short* __restrict__ w2f,
                      int* __restrict__ bcnt, int N) {
    int gid = blockIdx.x * blockDim.x + threadIdx.x; // 65536 threads
    int nb16 = (((N + BNODES - 1) >> BSH) << 4);
    if (gid < nb16) bcnt[gid] = 0;
    if (gid < 32768) {
        int tid = gid;
        int j = tid & 7, lane = (tid >> 3) & 63, ct = (tid >> 9) & 15, kk = tid >> 13;
        int k = kk * 32 + (lane >> 4) * 8 + j;
        int c = ((ct >> 2) << 6) + ((lane & 15) << 2) + (ct & 3);
        float v = (c < 128) ? W1[k * 128 + c] : W1[(128 + k) * 128 + (c - 128)];
        w1f[tid] = f2bf(v);
    } else if (gid < 65536) {
        int tid = gid - 32768;
        int j = tid & 7, lane = (tid >> 3) & 63, ct = (tid >> 9) & 7, kk = tid >> 12;
        int k = kk * 32 + (lane >> 4) * 8 + j;
        int c = ((ct >> 1) << 5) + ((lane & 15) << 1) + (ct & 1);
        w2f[tid] = f2bf(W2[k * 128 + c]);
    }
}

// D2: blocks [0,NSORT) = two-phase binning sorters (dispatched FIRST -> co-resident
// with gemm blocks, overlapped). blocks [NSORT, NSORT+nb1) = gemm1.
// gemm1: M=N, K=128, Nout=256; block = 4 waves; wave w owns out-cols [w*64,w*64+64).
// Frag j of wave w holds actual col w*64 + 4*(lane&15) + j  ->  8B ushort4 stores.
__global__ __launch_bounds__(256, 4) void k_fat1(
    const float* __restrict__ x,
    const unsigned short* __restrict__ w1f,
    const float* __restrict__ b1,
    unsigned short* __restrict__ Ys,
    unsigned short* __restrict__ Yd,
    const int* __restrict__ esrc,
    const int* __restrict__ edst,
    int* __restrict__ bcnt,
    unsigned int* __restrict__ bslot,
    int N, int nTiles, int nb1, int E)
{
    const int tid = threadIdx.x;
    if ((int)blockIdx.x < NSORT) {
        // ---- two-phase binning sorter ----
        __shared__ int lcnt[1024];    // local per-bucket count, then cursor
        __shared__ int lbase[1024];   // global run base per bucket
        const int NB = (N + BNODES - 1) >> BSH;  // 782 <= 1024
        const int eper = (E + NSORT - 1) / NSORT;
        const int e0 = blockIdx.x * eper;
        int e1 = e0 + eper; if (e1 > E) e1 = E;
        for (int i = tid; i < 1024; i += 256) lcnt[i] = 0;
        __syncthreads();
        // phase 1: LDS histogram by bucket
        for (int i = e0 + tid; i < e1; i += 256)
            atomicAdd(&lcnt[edst[i] >> BSH], 1);
        __syncthreads();
        // phase 2: one global reservation atomic per touched bucket
        for (int c = tid; c < 1024; c += 256) {
            int lc = lcnt[c];
            lbase[c] = (lc > 0 && c < NB) ? atomicAdd(&bcnt[c << 4], lc) : 0;
            lcnt[c] = 0;                        // reuse as cursor
        }
        __syncthreads();
        // phase 3: scatter into reserved contiguous runs (edges L2-hot from phase 1)
        for (int i = e0 + tid; i < e1; i += 256) {
            int d = edst[i], b = d >> BSH;
            int lo = atomicAdd(&lcnt[b], 1);    // LDS cursor
            int p = lbase[b] + lo;
            if (p < BCAP) bslot[((long)b << 10) + p] =
                ((unsigned int)(d & (BNODES - 1)) << 16) | (unsigned int)esrc[i];
        }
        return;
    }
    // ---- gemm1 part ----
    const int w = tid >> 6, lane = tid & 63;
    const int quad = lane >> 4, col = lane & 15;

    short8 wf[4][4];
#pragma unroll
    for (int kk = 0; kk < 4; kk++)
#pragma unroll
        for (int j = 0; j < 4; j++)
            wf[kk][j] = ((const short8*)w1f)[(kk * 16 + w * 4 + j) * 64 + lane];
    float4 bias = make_float4(0.f, 0.f, 0.f, 0.f);
    if (w >= 2) bias = *(const float4*)(b1 + (w - 2) * 64 + col * 4);
    unsigned short* Yhalf = (w < 2) ? Ys : Yd;
    const int cb = (w & 1) * 64;

    for (int t = blockIdx.x - NSORT; t < nTiles; t += nb1) {
        const int n0 = t * 16;
        const int nr = n0 + col;                 // N % 16 == 0
        const float* xrow = x + (long)nr * D;
        float4 f[8];
#pragma unroll
        for (int kk = 0; kk < 4; kk++) {
            f[kk * 2]     = *(const float4*)(xrow + kk * 32 + quad * 8);
            f[kk * 2 + 1] = *(const float4*)(xrow + kk * 32 + quad * 8 + 4);
        }
        floatx4 acc[4];
#pragma unroll
        for (int j = 0; j < 4; j++)
#pragma unroll
            for (int q = 0; q < 4; q++) acc[j][q] = 0.f;
#pragma unroll
        for (int kk = 0; kk < 4; kk++) {
            union { short8 s; unsigned int u[4]; } au;
            asm("v_cvt_pk_bf16_f32 %0, %1, %2" : "=v"(au.u[0]) : "v"(f[kk*2].x),   "v"(f[kk*2].y));
            asm("v_cvt_pk_bf16_f32 %0, %1, %2" : "=v"(au.u[1]) : "v"(f[kk*2].z),   "v"(f[kk*2].w));
            asm("v_cvt_pk_bf16_f32 %0, %1, %2" : "=v"(au.u[2]) : "v"(f[kk*2+1].x), "v"(f[kk*2+1].y));
            asm("v_cvt_pk_bf16_f32 %0, %1, %2" : "=v"(au.u[3]) : "v"(f[kk*2+1].z), "v"(f[kk*2+1].w));
#pragma unroll
            for (int j = 0; j < 4; j++)
                acc[j] = __builtin_amdgcn_mfma_f32_16x16x32_bf16(au.s, wf[kk][j], acc[j], 0, 0, 0);
        }
#pragma unroll
        for (int r = 0; r < 4; r++) {
            int n = n0 + quad * 4 + r;
            ushort4 o;
            o.x = f2bf(acc[0][r] + bias.x);
            o.y = f2bf(acc[1][r] + bias.y);
            o.z = f2bf(acc[2][r] + bias.z);
            o.w = f2bf(acc[3][r] + bias.w);
            *(ushort4*)(Yhalf + (long)n * D + cb + col * 4) = o;
        }
    }
}

// D3: one 512-thread block per bucket of 64 dst nodes.
// Phase A: stage packed slots into LDS, counting-sort by local dst (64 LDS counters
// + one 64-lane shfl scan). Phase B: 8 waves x 8 nodes; per node: register scalar
// accumulation, 8 independent 256B Ys row reads in flight, src indices broadcast-
// read from the sorted LDS list. Contiguous agg row writes.
__global__ __launch_bounds__(512, 2) void k_agg(
    const unsigned short* __restrict__ Ys,
    const unsigned short* __restrict__ Yd,
    const int* __restrict__ bcnt,
    const unsigned int* __restrict__ bslot,
    unsigned short* __restrict__ aggb, int N)
{
    __shared__ unsigned int eb[BCAP];          // 4 KB
    __shared__ unsigned short sorted[BCAP];    // 2 KB
    __shared__ int cnt64[BNODES], start64[BNODES], cur64[BNODES];
    const int tid = threadIdx.x, w = tid >> 6, lane = tid & 63;
    const int b = blockIdx.x, nb0 = b << BSH;
    int nd = N - nb0; if (nd > BNODES) nd = BNODES;
    int bc = bcnt[b << 4]; if (bc > BCAP) bc = BCAP;

    if (tid < BNODES) cnt64[tid] = 0;
    __syncthreads();
    for (int i = tid; i < bc; i += 512) {
        unsigned int e = bslot[((long)b << 10) + i];
        eb[i] = e;
        atomicAdd(&cnt64[e >> 16], 1);
    }
    __syncthreads();
    if (tid < 64) {
        int c = cnt64[tid];
        int incl = c;
#pragma unroll
        for (int off = 1; off < 64; off <<= 1) {
            int t = __shfl_up(incl, off, 64);
            if (lane >= off) incl += t;
        }
        start64[tid] = incl - c;
        cur64[tid] = incl - c;
    }
    __syncthreads();
    for (int i = tid; i < bc; i += 512) {
        unsigned int e = eb[i];
        int p = atomicAdd(&cur64[e >> 16], 1);
        sorted[p] = (unsigned short)(e & 0xffffu);
    }
    __syncthreads();

    const unsigned short* ysl = Ys + lane * 2;
#pragma unroll
    for (int k = 0; k < 8; k++) {
        int ln = w * 8 + k;
        if (ln >= nd) break;
        const int node = nb0 + ln;
        const int deg = cnt64[ln], base = start64[ln];
        unsigned int ydu = *(const unsigned int*)(Yd + (long)node * D + lane * 2);
        float yd0 = bflo(ydu), yd1 = bfhi(ydu);
        float a0 = 0.f, a1 = 0.f;
        int e = 0;
        for (; e + 8 <= deg; e += 8) {
            int s[8]; unsigned int u[8];
#pragma unroll
            for (int q = 0; q < 8; q++) s[q] = sorted[base + e + q];
#pragma unroll
            for (int q = 0; q < 8; q++) u[q] = *(const unsigned int*)(ysl + (long)s[q] * D);
#pragma unroll
            for (int q = 0; q < 8; q++) {
                a0 += fmaxf(bflo(u[q]) + yd0, 0.f);
                a1 += fmaxf(bfhi(u[q]) + yd1, 0.f);
            }
        }
        for (; e + 4 <= deg; e += 4) {
            int s[4]; unsigned int u[4];
#pragma unroll
            for (int q = 0; q < 4; q++) s[q] = sorted[base + e + q];
#pragma unroll
            for (int q = 0; q < 4; q++) u[q] = *(const unsigned int*)(ysl + (long)s[q] * D);
#pragma unroll
            for (int q = 0; q < 4; q++) {
                a0 += fmaxf(bflo(u[q]) + yd0, 0.f);
                a1 += fmaxf(bfhi(u[q]) + yd1, 0.f);
            }
        }
        for (; e < deg; e++) {
            unsigned int u0 = *(const unsigned int*)(ysl + (long)sorted[base + e] * D);
            a0 += fmaxf(bflo(u0) + yd0, 0.f);
            a1 += fmaxf(bfhi(u0) + yd1, 0.f);
        }
        unsigned int o = (unsigned int)f2bf(a0) | ((unsigned int)f2bf(a1) << 16);
        *(unsigned int*)(aggb + (long)node * D + lane * 2) = o;
    }
}

// D4: out = x + relu([x;agg]@W2 + b2). M=N, K=256, Nout=128. A-operand for K<128
// converted from fp32 x in-register. Block = 4 waves; wave w owns out-cols [w*32,w*32+32).
// Frag c of wave w holds actual col w*32 + 2*(lane&15) + c  ->  8B float2 stores.
__global__ __launch_bounds__(256, 4) void k_gemm2(
    const float* __restrict__ x,
    const unsigned short* __restrict__ aggb,
    const unsigned short* __restrict__ w2f,
    const float* __restrict__ b2,
    float* __restrict__ out,
    int N, int nTiles)
{
    const int tid = threadIdx.x, w = tid >> 6, lane = tid & 63;
    const int quad = lane >> 4, col = lane & 15;

    short8 wf[8][2];
#pragma unroll
    for (int kk = 0; kk < 8; kk++)
#pragma unroll
        for (int c = 0; c < 2; c++)
            wf[kk][c] = ((const short8*)w2f)[(kk * 8 + w * 2 + c) * 64 + lane];
    float2 bias = *(const float2*)(b2 + w * 32 + col * 2);

    for (int t = blockIdx.x; t < nTiles; t += gridDim.x) {
        const int n0 = t * 16;
        const int nr = n0 + col;                 // N % 16 == 0
        const float* xrow = x + (long)nr * D;
        float4 f[8];
        short8 ag[4];
#pragma unroll
        for (int kk = 0; kk < 4; kk++) {
            f[kk * 2]     = *(const float4*)(xrow + kk * 32 + quad * 8);
            f[kk * 2 + 1] = *(const float4*)(xrow + kk * 32 + quad * 8 + 4);
        }
#pragma unroll
        for (int kk = 0; kk < 4; kk++)
            ag[kk] = *(const short8*)(aggb + (long)nr * D + kk * 32 + quad * 8);
        floatx4 acc[2];
#pragma unroll
        for (int c = 0; c < 2; c++)
#pragma unroll
            for (int q = 0; q < 4; q++) acc[c][q] = 0.f;
#pragma unroll
        for (int kk = 0; kk < 4; kk++) {
            union { short8 s; unsigned int u[4]; } au;
            asm("v_cvt_pk_bf16_f32 %0, %1, %2" : "=v"(au.u[0]) : "v"(f[kk*2].x),   "v"(f[kk*2].y));
            asm("v_cvt_pk_bf16_f32 %0, %1, %2" : "=v"(au.u[1]) : "v"(f[kk*2].z),   "v"(f[kk*2].w));
            asm("v_cvt_pk_bf16_f32 %0, %1, %2" : "=v"(au.u[2]) : "v"(f[kk*2+1].x), "v"(f[kk*2+1].y));
            asm("v_cvt_pk_bf16_f32 %0, %1, %2" : "=v"(au.u[3]) : "v"(f[kk*2+1].z), "v"(f[kk*2+1].w));
            acc[0] = __builtin_amdgcn_mfma_f32_16x16x32_bf16(au.s, wf[kk][0], acc[0], 0, 0, 0);
            acc[1] = __builtin_amdgcn_mfma_f32_16x16x32_bf16(au.s, wf[kk][1], acc[1], 0, 0, 0);
        }
#pragma unroll
        for (int kk = 4; kk < 8; kk++) {
            acc[0] = __builtin_amdgcn_mfma_f32_16x16x32_bf16(ag[kk - 4], wf[kk][0], acc[0], 0, 0, 0);
            acc[1] = __builtin_amdgcn_mfma_f32_16x16x32_bf16(ag[kk - 4], wf[kk][1], acc[1], 0, 0, 0);
        }
#pragma unroll
        for (int r = 0; r < 4; r++) {
            int n = n0 + quad * 4 + r;
            long off = (long)n * D + w * 32 + col * 2;
            float2 xr = *(const float2*)(x + off);
            float v0 = fmaxf(acc[0][r] + bias.x, 0.f);
            float v1 = fmaxf(acc[1][r] + bias.y, 0.f);
            *(float2*)(out + off) = make_float2(xr.x + v0, xr.y + v1);
        }
    }
}

extern "C" void kernel_launch(void* const* d_in, const int* in_sizes, int n_in,
                              void* d_out, int out_size, void* d_ws, size_t ws_size,
                              hipStream_t stream)
{
    const float* x   = (const float*)d_in[0];
    const int* esrc  = (const int*)d_in[1];
    const int* edst  = (const int*)d_in[2];
    const float* W1  = (const float*)d_in[3];
    const float* b1  = (const float*)d_in[4];
    const float* W2  = (const float*)d_in[5];
    const float* b2  = (const float*)d_in[6];
    float* out = (float*)d_out;

    const int ND = in_sizes[0];     // N*D
    const int N  = ND / D;          // 50000
    const int E  = in_sizes[1];     // 600000

    // workspace carve-out (256B-aligned chunks), ~45 MB
    char* p = (char*)d_ws;
    auto alloc = [&](size_t bytes) { char* r = p; p += (bytes + 255) & ~(size_t)255; return r; };
    unsigned short* Ys   = (unsigned short*)alloc((size_t)ND * 2);
    unsigned short* Yd   = (unsigned short*)alloc((size_t)ND * 2);
    unsigned short* aggb = (unsigned short*)alloc((size_t)ND * 2);
    unsigned short* w1f  = (unsigned short*)alloc(32768 * 2);
    unsigned short* w2f  = (unsigned short*)alloc(32768 * 2);

    const int NB = (N + BNODES - 1) >> BSH;          // 782 buckets
    int* bcnt           = (int*)alloc((size_t)NB * 16 * 4);     // padded: 1 counter / 64B
    unsigned int* bslot = (unsigned int*)alloc((size_t)NB * BCAP * 4);

    const int nTiles = N / 16;              // 3125 (N % 16 == 0)
    const int nb1 = (nTiles + 2) / 3;       // 1042: each gemm block does <=3 tiles

    k_pre<<<256, 256, 0, stream>>>(W1, W2, w1f, w2f, bcnt, N);
    k_fat1<<<NSORT + nb1, 256, 0, stream>>>(x, w1f, b1, Ys, Yd, esrc, edst, bcnt, bslot,
                                            N, nTiles, nb1, E);
    k_agg<<<NB, 512, 0, stream>>>(Ys, Yd, bcnt, bslot, aggb, N);
    k_gemm2<<<nb1, 256, 0, stream>>>(x, aggb, w2f, b2, out, N, nTiles);
}

// Round 12
// 173.321 us; speedup vs baseline: 3.9420x; 1.0622x over previous
//
#include <hip/hip_runtime.h>
#include <stdint.h>

// RelationalMSG decomposed, 5 dispatches (split for attribution after r6-r11's
// fused k_fat1 resisted 6 rounds of subtraction-based inference):
//   D1 k_pre:   zero bucket counters + convert W1/W2 -> MFMA B-frag layout (bf16)
//   D2 k_sort:  64 blocks x 1024 threads two-phase binning: LDS histogram over
//               1024 bucket counters (edges STAGED in LDS, packed 32-bit
//               (bucket<<22)|(dstLocal<<16)|src) -> ONE global atomicAdd per
//               (block,bucket) run reservation (50K device atomics, not 600K) ->
//               LDS-cursor scatter from the LDS stage (NO global re-read).
//   D3 k_gemm1: Ys = x@W1a, Yd = x@W1b + b1 (x cvt in-reg) — pure, measurable.
//   D4 k_agg:   one 512-thread block per bucket: counting-sort by local dst in
//               LDS, then 8 waves x 8 nodes register-scalar gather (8 independent
//               256B Ys row loads in flight).
//   D5 k_gemm2: out = x + relu([x;agg]@W2 + b2)  (x cvt in-reg; no xb buffer)
// N=50000 (16 | N), E=600000, D=128. Edges/bucket ~Poisson(768), BCAP=1024 is
// 9 sigma (write-guarded; cannot corrupt memory).
// Lessons: no grid.sync (~50us/barrier); 600K device atomics = 35-40us regardless
// of locality (r3-r10); per-element LDS atomics catastrophic (r9, 531us); LDS
// counting-sort + register gather is the right agg structure (r10); low-width
// sorter tails dominate fused kernels (r11: occupancy 13%).

typedef __attribute__((ext_vector_type(8))) short short8;   // 8 bf16 (MFMA A/B frag)
typedef __attribute__((ext_vector_type(4))) float floatx4;  // MFMA C/D frag

#define D 128
#define BSH 6              // 64 nodes per bucket
#define BNODES 64
#define BCAP 1024
#define NSORT 64           // sorter blocks (50K reservation atomics total)

static __device__ __forceinline__ unsigned short f2bf(float f) {
    union { float f; unsigned int u; } v; v.f = f;
    unsigned int r = (v.u + 0x7fffu + ((v.u >> 16) & 1u)) >> 16; // RNE
    return (unsigned short)r;
}
static __device__ __forceinline__ float bflo(unsigned int u) {
    union { unsigned int u; float f; } v; v.u = u << 16; return v.f;
}
static __device__ __forceinline__ float bfhi(unsigned int u) {
    union { unsigned int u; float f; } v; v.u = u & 0xffff0000u; return v.f;
}

// B-fragment layouts (column-PERMUTED so each lane's frags hold ADJACENT output cols):
// w1f (gemm1, K=128, 256 out cols): frag[(kk*16+ct)*64+lane][j] =
//      B1[kk*32+(lane>>4)*8+j][ (ct>>2)*64 + 4*(lane&15) + (ct&3) ]
//   B1[k][c] = c<128 ? W1[k][c] : W1[128+k][c-128]   (W1 is [256][128])
// w2f (gemm2, K=256, 128 out cols): frag[(kk*8+ct)*64+lane][j] =
//      W2[kk*32+(lane>>4)*8+j][ (ct>>1)*32 + 2*(lane&15) + (ct&1) ]
// Also zeroes the padded bucket counters (NB*16 ints).
__global__ void k_pre(const float* __restrict__ W1, const float* __restrict__ W2,
                      unsigned short* __restrict__ w1f, unsigned short* __restrict__ w2f,
                      int* __restrict__ bcnt, int N) {
    int gid = blockIdx.x * blockDim.x + threadIdx.x; // 65536 threads
    int nb16 = (((N + BNODES - 1) >> BSH) << 4);
    if (gid < nb16) bcnt[gid] = 0;
    if (gid < 32768) {
        int tid = gid;
        int j = tid & 7, lane = (tid >> 3) & 63, ct = (tid >> 9) & 15, kk = tid >> 13;
        int k = kk * 32 + (lane >> 4) * 8 + j;
        int c = ((ct >> 2) << 6) + ((lane & 15) << 2) + (ct & 3);
        float v = (c < 128) ? W1[k * 128 + c] : W1[(128 + k) * 128 + (c - 128)];
        w1f[tid] = f2bf(v);
    } else if (gid < 65536) {
        int tid = gid - 32768;
        int j = tid & 7, lane = (tid >> 3) & 63, ct = (tid >> 9) & 7, kk = tid >> 12;
        int k = kk * 32 + (lane >> 4) * 8 + j;
        int c = ((ct >> 1) << 5) + ((lane & 15) << 1) + (ct & 1);
        w2f[tid] = f2bf(W2[k * 128 + c]);
    }
}

// D2: two-phase binning, 64 blocks x 1024 threads (16 waves/block for latency
// hiding). Edges staged in LDS during phase 1; phase 3 scatters from LDS only.
__global__ __launch_bounds__(1024) void k_sort(
    const int* __restrict__ esrc,
    const int* __restrict__ edst,
    int* __restrict__ bcnt,
    unsigned int* __restrict__ bslot,
    int N, int E)
{
    __shared__ unsigned int eb[9376];     // staged packed edges (eper<=9375)
    __shared__ int lcnt[1024];            // per-bucket count, then cursor
    __shared__ int lbase[1024];           // reserved global run base
    const int tid = threadIdx.x;
    const int NB = (N + BNODES - 1) >> BSH;  // 782 <= 1024
    const int eper = (E + NSORT - 1) / NSORT;
    const int e0 = blockIdx.x * eper;
    int e1 = e0 + eper; if (e1 > E) e1 = E;
    const int ne = e1 - e0;
    lcnt[tid] = 0;                        // blockDim == 1024
    __syncthreads();
    // phase 1: load + pack + LDS stage + LDS histogram
    for (int i = tid; i < ne; i += 1024) {
        int d = edst[e0 + i], s = esrc[e0 + i];
        int b = d >> BSH;
        eb[i] = ((unsigned int)b << 22) | ((unsigned int)(d & (BNODES - 1)) << 16)
              | (unsigned int)s;
        atomicAdd(&lcnt[b], 1);
    }
    __syncthreads();
    // phase 2: one global reservation atomic per touched bucket
    {
        int lc = lcnt[tid];
        lbase[tid] = (lc > 0 && tid < NB) ? atomicAdd(&bcnt[tid << 4], lc) : 0;
        lcnt[tid] = 0;                    // reuse as cursor
    }
    __syncthreads();
    // phase 3: scatter from LDS stage into reserved contiguous runs
    for (int i = tid; i < ne; i += 1024) {
        unsigned int wrd = eb[i];
        int b = wrd >> 22;
        int lo = atomicAdd(&lcnt[b], 1);
        int p = lbase[b] + lo;
        if (p < BCAP) bslot[((long)b << 10) + p] = wrd & 0x3fffffu;
    }
}

// D3: gemm1, M=N, K=128, Nout=256. Block = 4 waves; wave w owns out-cols
// [w*64,w*64+64). Frag j of wave w holds col w*64 + 4*(lane&15) + j -> 8B stores.
__global__ __launch_bounds__(256, 4) void k_gemm1(
    const float* __restrict__ x,
    const unsigned short* __restrict__ w1f,
    const float* __restrict__ b1,
    unsigned short* __restrict__ Ys,
    unsigned short* __restrict__ Yd,
    int N, int nTiles)
{
    const int tid = threadIdx.x;
    const int w = tid >> 6, lane = tid & 63;
    const int quad = lane >> 4, col = lane & 15;

    short8 wf[4][4];
#pragma unroll
    for (int kk = 0; kk < 4; kk++)
#pragma unroll
        for (int j = 0; j < 4; j++)
            wf[kk][j] = ((const short8*)w1f)[(kk * 16 + w * 4 + j) * 64 + lane];
    float4 bias = make_float4(0.f, 0.f, 0.f, 0.f);
    if (w >= 2) bias = *(const float4*)(b1 + (w - 2) * 64 + col * 4);
    unsigned short* Yhalf = (w < 2) ? Ys : Yd;
    const int cb = (w & 1) * 64;

    for (int t = blockIdx.x; t < nTiles; t += gridDim.x) {
        const int n0 = t * 16;
        const int nr = n0 + col;                 // N % 16 == 0
        const float* xrow = x + (long)nr * D;
        float4 f[8];
#pragma unroll
        for (int kk = 0; kk < 4; kk++) {
            f[kk * 2]     = *(const float4*)(xrow + kk * 32 + quad * 8);
            f[kk * 2 + 1] = *(const float4*)(xrow + kk * 32 + quad * 8 + 4);
        }
        floatx4 acc[4];
#pragma unroll
        for (int j = 0; j < 4; j++)
#pragma unroll
            for (int q = 0; q < 4; q++) acc[j][q] = 0.f;
#pragma unroll
        for (int kk = 0; kk < 4; kk++) {
            union { short8 s; unsigned int u[4]; } au;
            asm("v_cvt_pk_bf16_f32 %0, %1, %2" : "=v"(au.u[0]) : "v"(f[kk*2].x),   "v"(f[kk*2].y));
            asm("v_cvt_pk_bf16_f32 %0, %1, %2" : "=v"(au.u[1]) : "v"(f[kk*2].z),   "v"(f[kk*2].w));
            asm("v_cvt_pk_bf16_f32 %0, %1, %2" : "=v"(au.u[2]) : "v"(f[kk*2+1].x), "v"(f[kk*2+1].y));
            asm("v_cvt_pk_bf16_f32 %0, %1, %2" : "=v"(au.u[3]) : "v"(f[kk*2+1].z), "v"(f[kk*2+1].w));
#pragma unroll
            for (int j = 0; j < 4; j++)
                acc[j] = __builtin_amdgcn_mfma_f32_16x16x32_bf16(au.s, wf[kk][j], acc[j], 0, 0, 0);
        }
#pragma unroll
        for (int r = 0; r < 4; r++) {
            int n = n0 + quad * 4 + r;
            ushort4 o;
            o.x = f2bf(acc[0][r] + bias.x);
            o.y = f2bf(acc[1][r] + bias.y);
            o.z = f2bf(acc[2][r] + bias.z);
            o.w = f2bf(acc[3][r] + bias.w);
            *(ushort4*)(Yhalf + (long)n * D + cb + col * 4) = o;
        }
    }
}

// D4: one 512-thread block per bucket of 64 dst nodes.
// Phase A: stage packed slots into LDS, counting-sort by local dst (64 LDS counters
// + one 64-lane shfl scan). Phase B: 8 waves x 8 nodes; per node: register scalar
// accumulation, 8 independent 256B Ys row reads in flight. Contiguous row writes.
__global__ __launch_bounds__(512, 2) void k_agg(
    const unsigned short* __restrict__ Ys,
    const unsigned short* __restrict__ Yd,
    const int* __restrict__ bcnt,
    const unsigned int* __restrict__ bslot,
    unsigned short* __restrict__ aggb, int N)
{
    __shared__ unsigned int eb[BCAP];          // 4 KB
    __shared__ unsigned short sorted[BCAP];    // 2 KB
    __shared__ int cnt64[BNODES], start64[BNODES], cur64[BNODES];
    const int tid = threadIdx.x, w = tid >> 6, lane = tid & 63;
    const int b = blockIdx.x, nb0 = b << BSH;
    int nd = N - nb0; if (nd > BNODES) nd = BNODES;
    int bc = bcnt[b << 4]; if (bc > BCAP) bc = BCAP;

    if (tid < BNODES) cnt64[tid] = 0;
    __syncthreads();
    for (int i = tid; i < bc; i += 512) {
        unsigned int e = bslot[((long)b << 10) + i];
        eb[i] = e;
        atomicAdd(&cnt64[e >> 16], 1);
    }
    __syncthreads();
    if (tid < 64) {
        int c = cnt64[tid];
        int incl = c;
#pragma unroll
        for (int off = 1; off < 64; off <<= 1) {
            int t = __shfl_up(incl, off, 64);
            if (lane >= off) incl += t;
        }
        start64[tid] = incl - c;
        cur64[tid] = incl - c;
    }
    __syncthreads();
    for (int i = tid; i < bc; i += 512) {
        unsigned int e = eb[i];
        int p = atomicAdd(&cur64[e >> 16], 1);
        sorted[p] = (unsigned short)(e & 0xffffu);
    }
    __syncthreads();

    const unsigned short* ysl = Ys + lane * 2;
#pragma unroll
    for (int k = 0; k < 8; k++) {
        int ln = w * 8 + k;
        if (ln >= nd) break;
        const int node = nb0 + ln;
        const int deg = cnt64[ln], base = start64[ln];
        unsigned int ydu = *(const unsigned int*)(Yd + (long)node * D + lane * 2);
        float yd0 = bflo(ydu), yd1 = bfhi(ydu);
        float a0 = 0.f, a1 = 0.f;
        int e = 0;
        for (; e + 8 <= deg; e += 8) {
            int s[8]; unsigned int u[8];
#pragma unroll
            for (int q = 0; q < 8; q++) s[q] = sorted[base + e + q];
#pragma unroll
            for (int q = 0; q < 8; q++) u[q] = *(const unsigned int*)(ysl + (long)s[q] * D);
#pragma unroll
            for (int q = 0; q < 8; q++) {
                a0 += fmaxf(bflo(u[q]) + yd0, 0.f);
                a1 += fmaxf(bfhi(u[q]) + yd1, 0.f);
            }
        }
        for (; e + 4 <= deg; e += 4) {
            int s[4]; unsigned int u[4];
#pragma unroll
            for (int q = 0; q < 4; q++) s[q] = sorted[base + e + q];
#pragma unroll
            for (int q = 0; q < 4; q++) u[q] = *(const unsigned int*)(ysl + (long)s[q] * D);
#pragma unroll
            for (int q = 0; q < 4; q++) {
                a0 += fmaxf(bflo(u[q]) + yd0, 0.f);
                a1 += fmaxf(bfhi(u[q]) + yd1, 0.f);
            }
        }
        for (; e < deg; e++) {
            unsigned int u0 = *(const unsigned int*)(ysl + (long)sorted[base + e] * D);
            a0 += fmaxf(bflo(u0) + yd0, 0.f);
            a1 += fmaxf(bfhi(u0) + yd1, 0.f);
        }
        unsigned int o = (unsigned int)f2bf(a0) | ((unsigned int)f2bf(a1) << 16);
        *(unsigned int*)(aggb + (long)node * D + lane * 2) = o;
    }
}

// D5: out = x + relu([x;agg]@W2 + b2). M=N, K=256, Nout=128. A-operand for K<128
// converted from fp32 x in-register. Block = 4 waves; wave w owns out-cols [w*32,w*32+32).
// Frag c of wave w holds actual col w*32 + 2*(lane&15) + c  ->  8B float2 stores.
__global__ __launch_bounds__(256, 4) void k_gemm2(
    const float* __restrict__ x,
    const unsigned short* __restrict__ aggb,
    const unsigned short* __restrict__ w2f,
    const float* __restrict__ b2,
    float* __restrict__ out,
    int N, int nTiles)
{
    const int tid = threadIdx.x, w = tid >> 6, lane = tid & 63;
    const int quad = lane >> 4, col = lane & 15;

    short8 wf[8][2];
#pragma unroll
    for (int kk = 0; kk < 8; kk++)
#pragma unroll
        for (int c = 0; c < 2; c++)
            wf[kk][c] = ((const short8*)w2f)[(kk * 8 + w * 2 + c) * 64 + lane];
    float2 bias = *(const float2*)(b2 + w * 32 + col * 2);

    for (int t = blockIdx.x; t < nTiles; t += gridDim.x) {
        const int n0 = t * 16;
        const int nr = n0 + col;                 // N % 16 == 0
        const float* xrow = x + (long)nr * D;
        float4 f[8];
        short8 ag[4];
#pragma unroll
        for (int kk = 0; kk < 4; kk++) {
            f[kk * 2]     = *(const float4*)(xrow + kk * 32 + quad * 8);
            f[kk * 2 + 1] = *(const float4*)(xrow + kk * 32 + quad * 8 + 4);
        }
#pragma unroll
        for (int kk = 0; kk < 4; kk++)
            ag[kk] = *(const short8*)(aggb + (long)nr * D + kk * 32 + quad * 8);
        floatx4 acc[2];
#pragma unroll
        for (int c = 0; c < 2; c++)
#pragma unroll
            for (int q = 0; q < 4; q++) acc[c][q] = 0.f;
#pragma unroll
        for (int kk = 0; kk < 4; kk++) {
            union { short8 s; unsigned int u[4]; } au;
            asm("v_cvt_pk_bf16_f32 %0, %1, %2" : "=v"(au.u[0]) : "v"(f[kk*2].x),   "v"(f[kk*2].y));
            asm("v_cvt_pk_bf16_f32 %0, %1, %2" : "=v"(au.u[1]) : "v"(f[kk*2].z),   "v"(f[kk*2].w));
            asm("v_cvt_pk_bf16_f32 %0, %1, %2" : "=v"(au.u[2]) : "v"(f[kk*2+1].x), "v"(f[kk*2+1].y));
            asm("v_cvt_pk_bf16_f32 %0, %1, %2" : "=v"(au.u[3]) : "v"(f[kk*2+1].z), "v"(f[kk*2+1].w));
            acc[0] = __builtin_amdgcn_mfma_f32_16x16x32_bf16(au.s, wf[kk][0], acc[0], 0, 0, 0);
            acc[1] = __builtin_amdgcn_mfma_f32_16x16x32_bf16(au.s, wf[kk][1], acc[1], 0, 0, 0);
        }
#pragma unroll
        for (int kk = 4; kk < 8; kk++) {
            acc[0] = __builtin_amdgcn_mfma_f32_16x16x32_bf16(ag[kk - 4], wf[kk][0], acc[0], 0, 0, 0);
            acc[1] = __builtin_amdgcn_mfma_f32_16x16x32_bf16(ag[kk - 4], wf[kk][1], acc[1], 0, 0, 0);
        }
#pragma unroll
        for (int r = 0; r < 4; r++) {
            int n = n0 + quad * 4 + r;
            long off = (long)n * D + w * 32 + col * 2;
            float2 xr = *(const float2*)(x + off);
            float v0 = fmaxf(acc[0][r] + bias.x, 0.f);
            float v1 = fmaxf(acc[1][r] + bias.y, 0.f);
            *(float2*)(out + off) = make_float2(xr.x + v0, xr.y + v1);
        }
    }
}

extern "C" void kernel_launch(void* const* d_in, const int* in_sizes, int n_in,
                              void* d_out, int out_size, void* d_ws, size_t ws_size,
                              hipStream_t stream)
{
    const float* x   = (const float*)d_in[0];
    const int* esrc  = (const int*)d_in[1];
    const int* edst  = (const int*)d_in[2];
    const float* W1  = (const float*)d_in[3];
    const float* b1  = (const float*)d_in[4];
    const float* W2  = (const float*)d_in[5];
    const float* b2  = (const float*)d_in[6];
    float* out = (float*)d_out;

    const int ND = in_sizes[0];     // N*D
    const int N  = ND / D;          // 50000
    const int E  = in_sizes[1];     // 600000

    // workspace carve-out (256B-aligned chunks), ~45 MB
    char* p = (char*)d_ws;
    auto alloc = [&](size_t bytes) { char* r = p; p += (bytes + 255) & ~(size_t)255; return r; };
    unsigned short* Ys   = (unsigned short*)alloc((size_t)ND * 2);
    unsigned short* Yd   = (unsigned short*)alloc((size_t)ND * 2);
    unsigned short* aggb = (unsigned short*)alloc((size_t)ND * 2);
    unsigned short* w1f  = (unsigned short*)alloc(32768 * 2);
    unsigned short* w2f  = (unsigned short*)alloc(32768 * 2);

    const int NB = (N + BNODES - 1) >> BSH;          // 782 buckets
    int* bcnt           = (int*)alloc((size_t)NB * 16 * 4);     // padded: 1 counter / 64B
    unsigned int* bslot = (unsigned int*)alloc((size_t)NB * BCAP * 4);

    const int nTiles = N / 16;              // 3125 (N % 16 == 0)
    const int nb1 = (nTiles + 2) / 3;       // 1042: each gemm block does <=3 tiles

    k_pre<<<256, 256, 0, stream>>>(W1, W2, w1f, w2f, bcnt, N);
    k_sort<<<NSORT, 1024, 0, stream>>>(esrc, edst, bcnt, bslot, N, E);
    k_gemm1<<<nb1, 256, 0, stream>>>(x, w1f, b1, Ys, Yd, N, nTiles);
    k_agg<<<NB, 512, 0, stream>>>(Ys, Yd, bcnt, bslot, aggb, N);
    k_gemm2<<<nb1, 256, 0, stream>>>(x, aggb, w2f, b2, out, N, nTiles);
}

// Round 13
// 171.958 us; speedup vs baseline: 3.9732x; 1.0079x over previous
//
#include <hip/hip_runtime.h>
#include <stdint.h>

// RelationalMSG decomposed, 3 dispatches:
//   D1 k_pre:     convert W1/W2 -> MFMA B-frag layout (bf16). Nothing else.
//   D2 k_fat:     blocks 0..255 = ATOMIC-FREE fixed-region sort (LDS histogram ->
//                 per-(block,bucket) counts cnt2 (fully overwritten, no zeroing) ->
//                 scatter into fixed region bslot[bucket*6144 + block*24 + i]).
//                 blocks 256.. = gemm1 (Ys = x@W1a, Yd = x@W1b + b1, x cvt in-reg).
//                 Sorters dispatched FIRST -> co-resident, no tail (r11 lesson).
//   D3 k_aggemm2: one 512-thread block per bucket of 64 dst nodes:
//                 merge 256 sub-lists (256-wide shfl scan) -> counting-sort by
//                 local dst in LDS (r10) -> register-scalar gather (r8, 8 Ys rows
//                 in flight) -> agg tile kept in XOR-SWIZZLED LDS -> gemm2 for the
//                 bucket's own 4 row-tiles. aggb buffer ELIMINATED (-25.6MB).
// N=50000 (16 | N), E=600000, D=128.
// Caps: per-(block,bucket) Poisson(3) -> SCAP=24 is +10sigma (P ~1e-10, guarded);
// per-bucket Poisson(768) -> BCAP=1024 is +9sigma (guarded).
// Lessons: no grid.sync (~50us/barrier); 600K device atomics = 35-40us regardless
// of locality (r3-r10) -> this version has ZERO device atomics; per-element LDS
// atomics catastrophic (r9); LDS counting-sort + register gather right (r10);
// sorter tails dominate fused kernels unless dispatched first (r11).

typedef __attribute__((ext_vector_type(8))) short short8;   // 8 bf16 (MFMA A/B frag)
typedef __attribute__((ext_vector_type(4))) float floatx4;  // MFMA C/D frag

#define D 128
#define BSH 6              // 64 nodes per bucket
#define BNODES 64
#define BCAP 1024
#define NSORT2 256         // sorter blocks
#define SCAP 24            // per-(sorter,bucket) region slots

static __device__ __forceinline__ unsigned short f2bf(float f) {
    union { float f; unsigned int u; } v; v.f = f;
    unsigned int r = (v.u + 0x7fffu + ((v.u >> 16) & 1u)) >> 16; // RNE
    return (unsigned short)r;
}
static __device__ __forceinline__ float bflo(unsigned int u) {
    union { unsigned int u; float f; } v; v.u = u << 16; return v.f;
}
static __device__ __forceinline__ float bfhi(unsigned int u) {
    union { unsigned int u; float f; } v; v.u = u & 0xffff0000u; return v.f;
}

// B-fragment layouts (column-PERMUTED so each lane's frags hold ADJACENT output cols):
// w1f (gemm1, K=128, 256 out cols): frag[(kk*16+ct)*64+lane][j] =
//      B1[kk*32+(lane>>4)*8+j][ (ct>>2)*64 + 4*(lane&15) + (ct&3) ]
//   B1[k][c] = c<128 ? W1[k][c] : W1[128+k][c-128]   (W1 is [256][128])
// w2f (gemm2, K=256, 128 out cols): frag[(kk*8+ct)*64+lane][j] =
//      W2[kk*32+(lane>>4)*8+j][ (ct>>1)*32 + 2*(lane&15) + (ct&1) ]
__global__ void k_pre(const float* __restrict__ W1, const float* __restrict__ W2,
                      unsigned short* __restrict__ w1f, unsigned short* __restrict__ w2f) {
    int gid = blockIdx.x * blockDim.x + threadIdx.x; // 65536 threads
    if (gid < 32768) {
        int tid = gid;
        int j = tid & 7, lane = (tid >> 3) & 63, ct = (tid >> 9) & 15, kk = tid >> 13;
        int k = kk * 32 + (lane >> 4) * 8 + j;
        int c = ((ct >> 2) << 6) + ((lane & 15) << 2) + (ct & 3);
        float v = (c < 128) ? W1[k * 128 + c] : W1[(128 + k) * 128 + (c - 128)];
        w1f[tid] = f2bf(v);
    } else {
        int tid = gid - 32768;
        int j = tid & 7, lane = (tid >> 3) & 63, ct = (tid >> 9) & 7, kk = tid >> 12;
        int k = kk * 32 + (lane >> 4) * 8 + j;
        int c = ((ct >> 1) << 5) + ((lane & 15) << 1) + (ct & 1);
        w2f[tid] = f2bf(W2[k * 128 + c]);
    }
}

// D2: blocks [0,NSORT2) = atomic-free fixed-region sorters; blocks [NSORT2,..) = gemm1.
// gemm1: M=N, K=128, Nout=256; block = 4 waves; wave w owns out-cols [w*64,w*64+64).
// Frag j of wave w holds actual col w*64 + 4*(lane&15) + j  ->  8B ushort4 stores.
__global__ __launch_bounds__(256, 4) void k_fat(
    const float* __restrict__ x,
    const unsigned short* __restrict__ w1f,
    const float* __restrict__ b1,
    unsigned short* __restrict__ Ys,
    unsigned short* __restrict__ Yd,
    const int* __restrict__ esrc,
    const int* __restrict__ edst,
    int* __restrict__ cnt2,
    unsigned int* __restrict__ bslot,
    int N, int nTiles, int nb1, int E, int NB)
{
    __shared__ unsigned int eb2[2344];   // staged packed edges (eper <= 2344)
    __shared__ int lcnt[1024];           // per-bucket count, then cursor
    const int tid = threadIdx.x;
    if ((int)blockIdx.x < NSORT2) {
        const int bid = blockIdx.x;
        const int eper = (E + NSORT2 - 1) / NSORT2;   // 2344
        const int e0 = bid * eper;
        int e1 = e0 + eper; if (e1 > E) e1 = E;
        const int ne = e1 - e0;
        for (int i = tid; i < 1024; i += 256) lcnt[i] = 0;
        __syncthreads();
        // phase 1: load + pack (b<<22 | dl<<16 | src) + LDS stage + LDS histogram
        for (int i = tid; i < ne; i += 256) {
            int d = edst[e0 + i], s = esrc[e0 + i];
            int b = d >> BSH;
            eb2[i] = ((unsigned int)b << 22) | ((unsigned int)(d & (BNODES - 1)) << 16)
                   | (unsigned int)s;
            atomicAdd(&lcnt[b], 1);
        }
        __syncthreads();
        // phase 2: write clamped counts (NO atomics, fully overwritten each run)
        for (int c = tid; c < 1024; c += 256) {
            if (c < NB) {
                int lc = lcnt[c]; if (lc > SCAP) lc = SCAP;
                cnt2[(long)c * NSORT2 + bid] = lc;
            }
            lcnt[c] = 0;                 // reuse as cursor
        }
        __syncthreads();
        // phase 3: scatter from LDS stage into this block's fixed regions
        for (int i = tid; i < ne; i += 256) {
            unsigned int wd = eb2[i];
            int b = wd >> 22;
            int lo = atomicAdd(&lcnt[b], 1);   // LDS cursor only
            if (lo < SCAP)
                bslot[(long)b * (NSORT2 * SCAP) + bid * SCAP + lo] = wd & 0x3fffffu;
        }
        return;
    }
    // ---- gemm1 part ----
    const int w = tid >> 6, lane = tid & 63;
    const int quad = lane >> 4, col = lane & 15;

    short8 wf[4][4];
#pragma unroll
    for (int kk = 0; kk < 4; kk++)
#pragma unroll
        for (int j = 0; j < 4; j++)
            wf[kk][j] = ((const short8*)w1f)[(kk * 16 + w * 4 + j) * 64 + lane];
    float4 bias = make_float4(0.f, 0.f, 0.f, 0.f);
    if (w >= 2) bias = *(const float4*)(b1 + (w - 2) * 64 + col * 4);
    unsigned short* Yhalf = (w < 2) ? Ys : Yd;
    const int cb = (w & 1) * 64;

    for (int t = blockIdx.x - NSORT2; t < nTiles; t += nb1) {
        const int n0 = t * 16;
        const int nr = n0 + col;                 // N % 16 == 0
        const float* xrow = x + (long)nr * D;
        float4 f[8];
#pragma unroll
        for (int kk = 0; kk < 4; kk++) {
            f[kk * 2]     = *(const float4*)(xrow + kk * 32 + quad * 8);
            f[kk * 2 + 1] = *(const float4*)(xrow + kk * 32 + quad * 8 + 4);
        }
        floatx4 acc[4];
#pragma unroll
        for (int j = 0; j < 4; j++)
#pragma unroll
            for (int q = 0; q < 4; q++) acc[j][q] = 0.f;
#pragma unroll
        for (int kk = 0; kk < 4; kk++) {
            union { short8 s; unsigned int u[4]; } au;
            asm("v_cvt_pk_bf16_f32 %0, %1, %2" : "=v"(au.u[0]) : "v"(f[kk*2].x),   "v"(f[kk*2].y));
            asm("v_cvt_pk_bf16_f32 %0, %1, %2" : "=v"(au.u[1]) : "v"(f[kk*2].z),   "v"(f[kk*2].w));
            asm("v_cvt_pk_bf16_f32 %0, %1, %2" : "=v"(au.u[2]) : "v"(f[kk*2+1].x), "v"(f[kk*2+1].y));
            asm("v_cvt_pk_bf16_f32 %0, %1, %2" : "=v"(au.u[3]) : "v"(f[kk*2+1].z), "v"(f[kk*2+1].w));
#pragma unroll
            for (int j = 0; j < 4; j++)
                acc[j] = __builtin_amdgcn_mfma_f32_16x16x32_bf16(au.s, wf[kk][j], acc[j], 0, 0, 0);
        }
#pragma unroll
        for (int r = 0; r < 4; r++) {
            int n = n0 + quad * 4 + r;
            ushort4 o;
            o.x = f2bf(acc[0][r] + bias.x);
            o.y = f2bf(acc[1][r] + bias.y);
            o.z = f2bf(acc[2][r] + bias.z);
            o.w = f2bf(acc[3][r] + bias.w);
            *(ushort4*)(Yhalf + (long)n * D + cb + col * 4) = o;
        }
    }
}

// D3: one 512-thread block per bucket of 64 dst nodes. Phases:
// A0: 256-wide scan of per-sorter counts. A1: merge sub-lists into contiguous LDS
// + dst histogram. A2: 64-scan + counting-sort by local dst. B: register-scalar
// gather (8 Ys rows in flight), result into XOR-swizzled LDS agg tile.
// C: gemm2 for this bucket's 4 row-tiles (2 tiles in parallel across 8 waves),
// A-operand x cvt in-reg + agg from LDS; residual epilogue to out.
__global__ __launch_bounds__(512, 4) void k_aggemm2(
    const float* __restrict__ x,
    const unsigned short* __restrict__ Ys,
    const unsigned short* __restrict__ Yd,
    const int* __restrict__ cnt2,
    const unsigned int* __restrict__ bslot,
    const unsigned short* __restrict__ w2f,
    const float* __restrict__ b2,
    float* __restrict__ out,
    int N)
{
    __shared__ unsigned int eb[BCAP];            // 4 KB
    __shared__ unsigned short sorted[BCAP];      // 2 KB
    __shared__ unsigned short agg_s[BNODES * D]; // 16 KB, XOR-swizzled rows
    __shared__ int cnt64[BNODES], start64[BNODES], cur64[BNODES];
    __shared__ int scnt[NSORT2], spre[NSORT2], wsum[5];
    const int tid = threadIdx.x, w = tid >> 6, lane = tid & 63;
    const int b = blockIdx.x, nb0 = b << BSH;
    int nd = N - nb0; if (nd > BNODES) nd = BNODES;
    char* ab = (char*)agg_s;

    // ---- A0: per-sorter counts + 256-wide exclusive scan ----
    int c = 0;
    if (tid < NSORT2) { c = cnt2[(long)b * NSORT2 + tid]; scnt[tid] = c; }
    int incl = c;
#pragma unroll
    for (int off = 1; off < 64; off <<= 1) {
        int t = __shfl_up(incl, off, 64);
        if (lane >= off) incl += t;
    }
    if (tid < NSORT2 && lane == 63) wsum[tid >> 6] = incl;
    if (tid < BNODES) cnt64[tid] = 0;
    __syncthreads();
    if (tid == 0) {
        int a = 0;
#pragma unroll
        for (int k2 = 0; k2 < 4; k2++) { int t = wsum[k2]; wsum[k2] = a; a += t; }
        wsum[4] = a;
    }
    __syncthreads();
    if (tid < NSORT2) spre[tid] = incl - c + wsum[tid >> 6];
    __syncthreads();
    int bc = wsum[4]; if (bc > BCAP) bc = BCAP;

    // ---- A1: merge sub-lists into contiguous eb + local-dst histogram ----
    {
        int s = tid & (NSORT2 - 1);
        int cs = scnt[s], bas = spre[s];
        const unsigned int* sp = bslot + (long)b * (NSORT2 * SCAP) + s * SCAP;
        for (int j = tid >> 8; j < cs; j += 2) {
            int p = bas + j;
            if (p < BCAP) {
                unsigned int e = sp[j];          // dl<<16 | src (22-bit masked)
                eb[p] = e;
                atomicAdd(&cnt64[e >> 16], 1);
            }
        }
    }
    __syncthreads();
    // ---- A2: 64-scan + counting-sort by local dst ----
    if (tid < 64) {
        int cc = cnt64[tid];
        int inc2 = cc;
#pragma unroll
        for (int off = 1; off < 64; off <<= 1) {
            int t = __shfl_up(inc2, off, 64);
            if (lane >= off) inc2 += t;
        }
        start64[tid] = inc2 - cc;
        cur64[tid] = inc2 - cc;
    }
    __syncthreads();
    for (int i = tid; i < bc; i += 512) {
        unsigned int e = eb[i];
        int p = atomicAdd(&cur64[e >> 16], 1);
        sorted[p] = (unsigned short)(e & 0xffffu);
    }
    __syncthreads();

    // ---- B: register-scalar gather per node; agg -> swizzled LDS ----
    const unsigned short* ysl = Ys + lane * 2;
#pragma unroll
    for (int k = 0; k < 8; k++) {
        int ln = w * 8 + k;
        if (ln >= nd) break;
        const int node = nb0 + ln;
        const int deg = cnt64[ln], base = start64[ln];
        unsigned int ydu = *(const unsigned int*)(Yd + (long)node * D + lane * 2);
        float yd0 = bflo(ydu), yd1 = bfhi(ydu);
        float a0 = 0.f, a1 = 0.f;
        int e = 0;
        for (; e + 8 <= deg; e += 8) {
            int s[8]; unsigned int u[8];
#pragma unroll
            for (int q = 0; q < 8; q++) s[q] = sorted[base + e + q];
#pragma unroll
            for (int q = 0; q < 8; q++) u[q] = *(const unsigned int*)(ysl + (long)s[q] * D);
#pragma unroll
            for (int q = 0; q < 8; q++) {
                a0 += fmaxf(bflo(u[q]) + yd0, 0.f);
                a1 += fmaxf(bfhi(u[q]) + yd1, 0.f);
            }
        }
        for (; e + 4 <= deg; e += 4) {
            int s[4]; unsigned int u[4];
#pragma unroll
            for (int q = 0; q < 4; q++) s[q] = sorted[base + e + q];
#pragma unroll
            for (int q = 0; q < 4; q++) u[q] = *(const unsigned int*)(ysl + (long)s[q] * D);
#pragma unroll
            for (int q = 0; q < 4; q++) {
                a0 += fmaxf(bflo(u[q]) + yd0, 0.f);
                a1 += fmaxf(bfhi(u[q]) + yd1, 0.f);
            }
        }
        for (; e < deg; e++) {
            unsigned int u0 = *(const unsigned int*)(ysl + (long)sorted[base + e] * D);
            a0 += fmaxf(bflo(u0) + yd0, 0.f);
            a1 += fmaxf(bfhi(u0) + yd1, 0.f);
        }
        unsigned int o = (unsigned int)f2bf(a0) | ((unsigned int)f2bf(a1) << 16);
        // swizzled write: canonical byte = 256*ln + 4*lane, ^= (ln&7)<<4
        *(unsigned int*)(ab + ((ln << 8) + ((lane << 2) ^ ((ln & 7) << 4)))) = o;
    }
    __syncthreads();

    // ---- C: gemm2 for this bucket's row-tiles (2 tiles across 8 waves) ----
    {
        const int quad = lane >> 4, col = lane & 15;
        const int cg = w & 3;                    // column group (32 out cols)
        short8 wf2[8][2];
#pragma unroll
        for (int kk = 0; kk < 8; kk++)
#pragma unroll
            for (int cc = 0; cc < 2; cc++)
                wf2[kk][cc] = ((const short8*)w2f)[(kk * 8 + cg * 2 + cc) * 64 + lane];
        float2 bias = *(const float2*)(b2 + cg * 32 + col * 2);

        for (int tile = (w >> 2); tile * 16 < nd; tile += 2) {
            const int n0 = nb0 + tile * 16;
            const int nr = n0 + col;
            const int row = tile * 16 + col;     // row within bucket; row&7 == col&7
            const float* xrow = x + (long)nr * D;
            float4 f[8];
            short8 ag[4];
#pragma unroll
            for (int kk = 0; kk < 4; kk++) {
                f[kk * 2]     = *(const float4*)(xrow + kk * 32 + quad * 8);
                f[kk * 2 + 1] = *(const float4*)(xrow + kk * 32 + quad * 8 + 4);
            }
#pragma unroll
            for (int kk = 0; kk < 4; kk++)
                ag[kk] = *(const short8*)(ab + ((row << 8)
                          + (((kk << 6) + (quad << 4)) ^ ((row & 7) << 4))));
            floatx4 acc[2];
#pragma unroll
            for (int cc = 0; cc < 2; cc++)
#pragma unroll
                for (int q = 0; q < 4; q++) acc[cc][q] = 0.f;
#pragma unroll
            for (int kk = 0; kk < 4; kk++) {
                union { short8 s; unsigned int u[4]; } au;
                asm("v_cvt_pk_bf16_f32 %0, %1, %2" : "=v"(au.u[0]) : "v"(f[kk*2].x),   "v"(f[kk*2].y));
                asm("v_cvt_pk_bf16_f32 %0, %1, %2" : "=v"(au.u[1]) : "v"(f[kk*2].z),   "v"(f[kk*2].w));
                asm("v_cvt_pk_bf16_f32 %0, %1, %2" : "=v"(au.u[2]) : "v"(f[kk*2+1].x), "v"(f[kk*2+1].y));
                asm("v_cvt_pk_bf16_f32 %0, %1, %2" : "=v"(au.u[3]) : "v"(f[kk*2+1].z), "v"(f[kk*2+1].w));
                acc[0] = __builtin_amdgcn_mfma_f32_16x16x32_bf16(au.s, wf2[kk][0], acc[0], 0, 0, 0);
                acc[1] = __builtin_amdgcn_mfma_f32_16x16x32_bf16(au.s, wf2[kk][1], acc[1], 0, 0, 0);
            }
#pragma unroll
            for (int kk = 4; kk < 8; kk++) {
                acc[0] = __builtin_amdgcn_mfma_f32_16x16x32_bf16(ag[kk - 4], wf2[kk][0], acc[0], 0, 0, 0);
                acc[1] = __builtin_amdgcn_mfma_f32_16x16x32_bf16(ag[kk - 4], wf2[kk][1], acc[1], 0, 0, 0);
            }
#pragma unroll
            for (int r = 0; r < 4; r++) {
                int n = n0 + quad * 4 + r;
                long off = (long)n * D + cg * 32 + col * 2;
                float2 xr = *(const float2*)(x + off);
                float v0 = fmaxf(acc[0][r] + bias.x, 0.f);
                float v1 = fmaxf(acc[1][r] + bias.y, 0.f);
                *(float2*)(out + off) = make_float2(xr.x + v0, xr.y + v1);
            }
        }
    }
}

extern "C" void kernel_launch(void* const* d_in, const int* in_sizes, int n_in,
                              void* d_out, int out_size, void* d_ws, size_t ws_size,
                              hipStream_t stream)
{
    const float* x   = (const float*)d_in[0];
    const int* esrc  = (const int*)d_in[1];
    const int* edst  = (const int*)d_in[2];
    const float* W1  = (const float*)d_in[3];
    const float* b1  = (const float*)d_in[4];
    const float* W2  = (const float*)d_in[5];
    const float* b2  = (const float*)d_in[6];
    float* out = (float*)d_out;

    const int ND = in_sizes[0];     // N*D
    const int N  = ND / D;          // 50000
    const int E  = in_sizes[1];     // 600000

    // workspace carve-out (256B-aligned chunks), ~46 MB
    char* p = (char*)d_ws;
    auto alloc = [&](size_t bytes) { char* r = p; p += (bytes + 255) & ~(size_t)255; return r; };
    unsigned short* Ys   = (unsigned short*)alloc((size_t)ND * 2);
    unsigned short* Yd   = (unsigned short*)alloc((size_t)ND * 2);
    unsigned short* w1f  = (unsigned short*)alloc(32768 * 2);
    unsigned short* w2f  = (unsigned short*)alloc(32768 * 2);

    const int NB = (N + BNODES - 1) >> BSH;          // 782 buckets
    int* cnt2           = (int*)alloc((size_t)NB * NSORT2 * 4);          // 800 KB
    unsigned int* bslot = (unsigned int*)alloc((size_t)NB * NSORT2 * SCAP * 4); // 19.2 MB

    const int nTiles = N / 16;              // 3125 (N % 16 == 0)
    const int nb1 = (nTiles + 2) / 3;       // 1042: each gemm block does <=3 tiles

    k_pre<<<256, 256, 0, stream>>>(W1, W2, w1f, w2f);
    k_fat<<<NSORT2 + nb1, 256, 0, stream>>>(x, w1f, b1, Ys, Yd, esrc, edst,
                                            cnt2, bslot, N, nTiles, nb1, E, NB);
    k_aggemm2<<<NB, 512, 0, stream>>>(x, Ys, Yd, cnt2, bslot, w2f, b2, out, N);
}